// Round 15
// baseline (4353.511 us; speedup 1.0000x reference)
//
#include <hip/hip_runtime.h>
#include <hip/hip_bf16.h>
#include <cmath>

#define NLAYERS 12
#define NHEADS  12
#define DM      768
#define VOCAB   50257
#define TSEQ    1024
#define BT      4096   // B*T
#define NCHUNK  786    // ceil(VOCAB/64) col-chunks for loss partials

typedef __attribute__((ext_vector_type(4))) float f32x4;
typedef __attribute__((ext_vector_type(8))) short bf16x8;
typedef __attribute__((ext_vector_type(4))) short s16x4;

typedef __hip_bfloat16 bf16;

#define MFMA16(a, b, c) __builtin_amdgcn_mfma_f32_16x16x32_bf16(a, b, c, 0, 0, 0)

// ---------------- helpers ----------------
__device__ __forceinline__ void gload16(const void* g, void* l) {
    __builtin_amdgcn_global_load_lds(
        (const __attribute__((address_space(1))) void*)g,
        (__attribute__((address_space(3))) void*)l, 16, 0, 0);
}

// raw s_barrier with compiler memory fences (no forced vmcnt(0) drain)
__device__ __forceinline__ void wg_barrier() {
    asm volatile("" ::: "memory");
    __builtin_amdgcn_s_barrier();
    asm volatile("" ::: "memory");
}

__device__ __forceinline__ float gelu_tanh(float v) {
    float u = 0.7978845608028654f * (v + 0.044715f * v * v * v);
    return 0.5f * v * (1.0f + tanhf(u));
}

__device__ __forceinline__ short f2bf(float f) {
    bf16 h = (bf16)f;
    return *reinterpret_cast<short*>(&h);
}

// ---- DPP 16-lane butterfly reductions (VALU-speed, no LDS/bpermute) ----
template<int CTRL>
__device__ __forceinline__ float dpp_mov(float x) {
    int i = __builtin_bit_cast(int, x);
    i = __builtin_amdgcn_mov_dpp(i, CTRL, 0xF, 0xF, false);
    return __builtin_bit_cast(float, i);
}
__device__ __forceinline__ float dpp_max16(float x) {
    x = fmaxf(x, dpp_mov<0xB1>(x));
    x = fmaxf(x, dpp_mov<0x4E>(x));
    x = fmaxf(x, dpp_mov<0x141>(x));
    x = fmaxf(x, dpp_mov<0x140>(x));
    return x;
}
__device__ __forceinline__ float dpp_sum16(float x) {
    x += dpp_mov<0xB1>(x);
    x += dpp_mov<0x4E>(x);
    x += dpp_mov<0x141>(x);
    x += dpp_mov<0x140>(x);
    return x;
}

struct ushort4s { short a, b, c, d; };

// ---------------- weight prep ----------------
__global__ void transpose_bf16_kernel(const float* __restrict__ in, bf16* __restrict__ out,
                                      int K, int N) {
    __shared__ float tile[32][33];
    size_t lofs = (size_t)blockIdx.z * K * N;
    int k0 = blockIdx.y * 32, n0 = blockIdx.x * 32;
    int tx = threadIdx.x, ty = threadIdx.y;      // 32x8
#pragma unroll
    for (int i = 0; i < 32; i += 8)
        tile[ty + i][tx] = in[lofs + (size_t)(k0 + ty + i) * N + n0 + tx];
    __syncthreads();
#pragma unroll
    for (int i = 0; i < 32; i += 8)
        out[lofs + (size_t)(n0 + ty + i) * K + k0 + tx] = (bf16)tile[tx][ty + i];
}

__global__ void tobf16_kernel(const float* __restrict__ in, bf16* __restrict__ out, size_t n4) {
    size_t i = (size_t)blockIdx.x * 256 + threadIdx.x;
    if (i < n4) {
        float4 f = reinterpret_cast<const float4*>(in)[i];
        s16x4 o = {f2bf(f.x), f2bf(f.y), f2bf(f.z), f2bf(f.w)};
        *reinterpret_cast<s16x4*>(out + i * 4) = o;
    }
}

// ---------------- embedding (fp32 residual stream, float4) ----------------
__global__ void embed_kernel(const int* __restrict__ inp, const float* __restrict__ wte,
                             const float* __restrict__ wpe, float* __restrict__ x) {
    int idx = blockIdx.x * 256 + threadIdx.x;    // over BT*DM/4
    int m = idx / (DM / 4), c4 = idx % (DM / 4);
    int tok = inp[m];
    int t = m & (TSEQ - 1);
    float4 a = reinterpret_cast<const float4*>(wte)[(size_t)tok * (DM / 4) + c4];
    float4 b = reinterpret_cast<const float4*>(wpe)[(size_t)t * (DM / 4) + c4];
    float4 o = {a.x + b.x, a.y + b.y, a.z + b.z, a.w + b.w};
    reinterpret_cast<float4*>(x)[idx] = o;
}

// ---------------- layernorm: one row per WAVE (no block sync) ----------------
__global__ __launch_bounds__(256) void ln_kernel(const float* __restrict__ x,
                                                 const float* __restrict__ w,
                                                 const float* __restrict__ b,
                                                 bf16* __restrict__ y) {
    int tid = threadIdx.x, wv = tid >> 6, lane = tid & 63;
    int row = blockIdx.x * 4 + wv;
    const float4* xr = reinterpret_cast<const float4*>(x + (size_t)row * DM);
    float4 v[3];
    float s = 0.f, q = 0.f;
#pragma unroll
    for (int j = 0; j < 3; ++j) {
        v[j] = xr[lane + 64 * j];
        s += v[j].x + v[j].y + v[j].z + v[j].w;
        q += v[j].x * v[j].x + v[j].y * v[j].y + v[j].z * v[j].z + v[j].w * v[j].w;
    }
#pragma unroll
    for (int o = 1; o < 64; o <<= 1) { s += __shfl_xor(s, o); q += __shfl_xor(q, o); }
    float mu  = s * (1.0f / DM);
    float var = q * (1.0f / DM) - mu * mu;
    float inv = rsqrtf(var + 1e-5f);
#pragma unroll
    for (int j = 0; j < 3; ++j) {
        int c4 = lane + 64 * j;
        float4 wv4 = reinterpret_cast<const float4*>(w)[c4];
        float4 bv4 = reinterpret_cast<const float4*>(b)[c4];
        ushort4s o;
        o.a = f2bf((v[j].x - mu) * inv * wv4.x + bv4.x);
        o.b = f2bf((v[j].y - mu) * inv * wv4.y + bv4.y);
        o.c = f2bf((v[j].z - mu) * inv * wv4.z + bv4.z);
        o.d = f2bf((v[j].w - mu) * inv * wv4.w + bv4.w);
        *reinterpret_cast<ushort4s*>(y + (size_t)row * DM + c4 * 4) = o;
    }
}

#define GF_GELU    1
#define GF_OBF16   2
#define GF_CLAMP   4
#define GF_PARTIAL 8

// ---------------- 128x128 GEMM, BK=64, 2-buffer 1-ahead, counted vmcnt ----------------
// 8 gload_lds per tile per thread -> vmcnt(8) while next tile in flight.
// Rows are 128 B (8 granules); full 8-way XOR swizzle both sides (rule #21).
template<int FLAGS, int TAG>
__global__ __launch_bounds__(256) void gemm_k(
    const bf16* __restrict__ A, const bf16* __restrict__ Bt,
    const float* __restrict__ bias, const float* __restrict__ resid,
    void* __restrict__ C, float2* __restrict__ partials,
    int M, int N, int K) {
    __shared__ short ldsA[2][128 * 64];
    __shared__ short ldsB[2][128 * 64];
    int tid = threadIdx.x;
    int lane = tid & 63, w = tid >> 6;
    int wm = w >> 1, wn = w & 1;
    int r = lane & 15, kq = lane >> 4;
    int bm = blockIdx.x * 128, bn = blockIdx.y * 128;

    f32x4 acc[4][4] = {};

    auto stage = [&](int buf, int kt) {
        int k0 = kt * 64;
#pragma unroll
        for (int i = 0; i < 4; ++i) {            // A: 128 rows x 8 granules = 1024 chunks
            int chunk = i * 256 + tid;
            int row = chunk >> 3;
            int gs = (chunk & 7) ^ (row & 7);
            gload16(A + (size_t)(bm + row) * K + k0 + gs * 8, &ldsA[buf][chunk * 8]);
        }
#pragma unroll
        for (int i = 0; i < 4; ++i) {            // B likewise
            int chunk = i * 256 + tid;
            int row = chunk >> 3;
            int gs = (chunk & 7) ^ (row & 7);
            gload16(Bt + (size_t)(bn + row) * K + k0 + gs * 8, &ldsB[buf][chunk * 8]);
        }
    };
    auto compute = [&](int buf) {
        __builtin_amdgcn_s_setprio(1);
#pragma unroll
        for (int kk = 0; kk < 2; ++kk) {
            bf16x8 af[4], bfr[4];
#pragma unroll
            for (int m = 0; m < 4; ++m) {
                int row = wm * 64 + m * 16 + r;
                af[m] = *reinterpret_cast<bf16x8*>(
                    &ldsA[buf][row * 64 + ((kk * 4 + kq) ^ (row & 7)) * 8]);
            }
#pragma unroll
            for (int n = 0; n < 4; ++n) {
                int row = wn * 64 + n * 16 + r;
                bfr[n] = *reinterpret_cast<bf16x8*>(
                    &ldsB[buf][row * 64 + ((kk * 4 + kq) ^ (row & 7)) * 8]);
            }
#pragma unroll
            for (int m = 0; m < 4; ++m)
#pragma unroll
                for (int n = 0; n < 4; ++n)
                    acc[m][n] = MFMA16(af[m], bfr[n], acc[m][n]);
        }
        __builtin_amdgcn_s_setprio(0);
    };

    const int NT = K / 64;
    stage(0, 0);
    int buf = 0;
    for (int t = 0; t < NT; ++t) {
        if (t + 1 < NT) {
            stage(buf ^ 1, t + 1);
            asm volatile("s_waitcnt vmcnt(8)" ::: "memory");   // tile t landed
        } else {
            asm volatile("s_waitcnt vmcnt(0)" ::: "memory");
        }
        wg_barrier();                    // tile t resident for ALL waves
        compute(buf);
        asm volatile("s_waitcnt lgkmcnt(0)" ::: "memory");     // my reads done
        wg_barrier();                    // buffer reusable
        buf ^= 1;
    }

    int row0 = bm + wm * 64, col0 = bn + wn * 64;
#pragma unroll
    for (int m = 0; m < 4; ++m) {
#pragma unroll
        for (int n = 0; n < 4; ++n) {
            int col = col0 + n * 16 + r;
#pragma unroll
            for (int rr = 0; rr < 4; ++rr) {
                int row = row0 + m * 16 + kq * 4 + rr;
                float v = acc[m][n][rr];
                if (bias) v += bias[col];
                if (FLAGS & GF_GELU) v = gelu_tanh(v);
                if (resid) v += resid[(size_t)row * N + col];
                if (FLAGS & GF_OBF16) ((bf16*)C)[(size_t)row * N + col] = (bf16)v;
                else                  ((float*)C)[(size_t)row * N + col] = v;
            }
        }
    }
}

// ---------------- 64x128 GEMM, BK=64, 2-buffer 1-ahead (proj / fc2) ----------------
// 6 gload_lds per tile per thread -> vmcnt(6). LDS 48 KB -> 3 blocks/CU.
template<int FLAGS, int TAG>
__global__ __launch_bounds__(256) void gemm_k64(
    const bf16* __restrict__ A, const bf16* __restrict__ Bt,
    const float* __restrict__ bias, const float* __restrict__ resid,
    void* __restrict__ C, float2* __restrict__ partials,
    int M, int N, int K) {
    __shared__ short ldsA[2][64 * 64];
    __shared__ short ldsB[2][128 * 64];
    int tid = threadIdx.x;
    int lane = tid & 63, w = tid >> 6;           // 4 waves, wave w: cols w*32..+31
    int r = lane & 15, kq = lane >> 4;
    int bm = blockIdx.x * 64, bn = blockIdx.y * 128;

    f32x4 acc[4][2] = {};

    auto stage = [&](int buf, int kt) {
        int k0 = kt * 64;
#pragma unroll
        for (int i = 0; i < 2; ++i) {            // A: 64 rows x 8 granules = 512 chunks
            int chunk = i * 256 + tid;
            int row = chunk >> 3;
            int gs = (chunk & 7) ^ (row & 7);
            gload16(A + (size_t)(bm + row) * K + k0 + gs * 8, &ldsA[buf][chunk * 8]);
        }
#pragma unroll
        for (int i = 0; i < 4; ++i) {            // B: 128 rows x 8 = 1024 chunks
            int chunk = i * 256 + tid;
            int row = chunk >> 3;
            int gs = (chunk & 7) ^ (row & 7);
            gload16(Bt + (size_t)(bn + row) * K + k0 + gs * 8, &ldsB[buf][chunk * 8]);
        }
    };
    auto compute = [&](int buf) {
        __builtin_amdgcn_s_setprio(1);
#pragma unroll
        for (int kk = 0; kk < 2; ++kk) {
            bf16x8 af[4], bfr[2];
#pragma unroll
            for (int m = 0; m < 4; ++m) {
                int row = m * 16 + r;
                af[m] = *reinterpret_cast<bf16x8*>(
                    &ldsA[buf][row * 64 + ((kk * 4 + kq) ^ (row & 7)) * 8]);
            }
#pragma unroll
            for (int n = 0; n < 2; ++n) {
                int row = w * 32 + n * 16 + r;
                bfr[n] = *reinterpret_cast<bf16x8*>(
                    &ldsB[buf][row * 64 + ((kk * 4 + kq) ^ (row & 7)) * 8]);
            }
#pragma unroll
            for (int m = 0; m < 4; ++m)
#pragma unroll
                for (int n = 0; n < 2; ++n)
                    acc[m][n] = MFMA16(af[m], bfr[n], acc[m][n]);
        }
        __builtin_amdgcn_s_setprio(0);
    };

    const int NT = K / 64;
    stage(0, 0);
    int buf = 0;
    for (int t = 0; t < NT; ++t) {
        if (t + 1 < NT) {
            stage(buf ^ 1, t + 1);
            asm volatile("s_waitcnt vmcnt(6)" ::: "memory");   // tile t landed
        } else {
            asm volatile("s_waitcnt vmcnt(0)" ::: "memory");
        }
        wg_barrier();
        compute(buf);
        asm volatile("s_waitcnt lgkmcnt(0)" ::: "memory");
        wg_barrier();
        buf ^= 1;
    }

    int col0 = bn + w * 32;
#pragma unroll
    for (int m = 0; m < 4; ++m) {
#pragma unroll
        for (int n = 0; n < 2; ++n) {
            int col = col0 + n * 16 + r;
#pragma unroll
            for (int rr = 0; rr < 4; ++rr) {
                int row = bm + m * 16 + kq * 4 + rr;
                float v = acc[m][n][rr];
                if (bias) v += bias[col];
                if (FLAGS & GF_GELU) v = gelu_tanh(v);
                if (resid) v += resid[(size_t)row * N + col];
                if (FLAGS & GF_OBF16) ((bf16*)C)[(size_t)row * N + col] = (bf16)v;
                else                  ((float*)C)[(size_t)row * N + col] = v;
            }
        }
    }
}

// ---------------- 128x256 GEMM, 8 waves x 64x64, 3-buffer 2-ahead (lm_head) ----------------
// NT stores for the fp32 logits (don't pollute L2; weight panels stay cached).
template<int FLAGS, int TAG>
__global__ __launch_bounds__(512, 4) void gemm_wide(
    const bf16* __restrict__ A, const bf16* __restrict__ Bt,
    const float* __restrict__ bias, const float* __restrict__ resid,
    void* __restrict__ C, float2* __restrict__ partials,
    int M, int N, int K) {
    __shared__ short ldsA[3][128 * 32];          // 3 x 8 KB
    __shared__ short ldsB[3][256 * 32];          // 3 x 16 KB
    int tid = threadIdx.x;                       // 0..511
    int lane = tid & 63, w = tid >> 6;
    int wm = w >> 2, wn = w & 3;                 // 2M x 4N waves, 64x64 each
    int r = lane & 15, kq = lane >> 4;
    int bm = blockIdx.x * 128, bn = blockIdx.y * 256;

    f32x4 acc[4][4] = {};

    auto stage = [&](int buf, int kt) {
        int k0 = kt * 32;
        {   // A tile: 512 chunks, 1 per thread
            int row = tid >> 2;
            int gs = (tid & 3) ^ ((row >> 1) & 3);
            gload16(A + (size_t)(bm + row) * K + k0 + gs * 8, &ldsA[buf][tid * 8]);
        }
#pragma unroll
        for (int i = 0; i < 2; ++i) {            // B tile: 1024 chunks, 2 per thread
            int chunk = i * 512 + tid;
            int row = chunk >> 2;
            int gs = (chunk & 3) ^ ((row >> 1) & 3);
            int grow = bn + row;
            if (FLAGS & GF_CLAMP) grow = min(grow, N - 1);
            gload16(Bt + (size_t)grow * K + k0 + gs * 8, &ldsB[buf][chunk * 8]);
        }
    };
    auto compute = [&](int buf) {
        bf16x8 af[4], bfr[4];
#pragma unroll
        for (int m = 0; m < 4; ++m) {
            int row = wm * 64 + m * 16 + r;
            af[m] = *reinterpret_cast<bf16x8*>(&ldsA[buf][row * 32 + (kq ^ ((row >> 1) & 3)) * 8]);
        }
#pragma unroll
        for (int n = 0; n < 4; ++n) {
            int row = wn * 64 + n * 16 + r;
            bfr[n] = *reinterpret_cast<bf16x8*>(&ldsB[buf][row * 32 + (kq ^ ((row >> 1) & 3)) * 8]);
        }
        __builtin_amdgcn_s_setprio(1);
#pragma unroll
        for (int m = 0; m < 4; ++m)
#pragma unroll
            for (int n = 0; n < 4; ++n)
                acc[m][n] = MFMA16(af[m], bfr[n], acc[m][n]);
        __builtin_amdgcn_s_setprio(0);
    };

    const int NT = K / 32;                       // 24
    stage(0, 0);
    stage(1, 1);
    for (int t = 0; t < NT; ++t) {
        if (t + 2 < NT) {
            stage((t + 2) % 3, t + 2);
            asm volatile("s_waitcnt vmcnt(6)" ::: "memory");   // tile t landed
        } else if (t + 1 < NT) {
            asm volatile("s_waitcnt vmcnt(3)" ::: "memory");
        } else {
            asm volatile("s_waitcnt vmcnt(0)" ::: "memory");
        }
        wg_barrier();
        compute(t % 3);
        asm volatile("s_waitcnt lgkmcnt(0)" ::: "memory");
        wg_barrier();
    }

    int row0 = bm + wm * 64, col0 = bn + wn * 64;
#pragma unroll
    for (int m = 0; m < 4; ++m) {
#pragma unroll
        for (int n = 0; n < 4; ++n) {
            int col = col0 + n * 16 + r;
            if (col < N) {
#pragma unroll
                for (int rr = 0; rr < 4; ++rr) {
                    int row = row0 + m * 16 + kq * 4 + rr;
                    float v = acc[m][n][rr];
                    if (bias) v += bias[col];
                    if (FLAGS & GF_GELU) v = gelu_tanh(v);
                    if (resid) v += resid[(size_t)row * N + col];
                    if (FLAGS & GF_OBF16) ((bf16*)C)[(size_t)row * N + col] = (bf16)v;
                    else __builtin_nontemporal_store(v, &((float*)C)[(size_t)row * N + col]);
                }
            }
        }
    }

    if (FLAGS & GF_PARTIAL) {
        int chunk = (bn >> 6) + wn;              // 64-col chunk index
        if (chunk < NCHUNK) {
#pragma unroll
            for (int m = 0; m < 4; ++m) {
#pragma unroll
                for (int rr = 0; rr < 4; ++rr) {
                    float vals[4], mx = -INFINITY;
#pragma unroll
                    for (int n = 0; n < 4; ++n) {
                        int col = col0 + n * 16 + r;
                        float v = (col < N) ? acc[m][n][rr] : -INFINITY;
                        vals[n] = v;
                        mx = fmaxf(mx, v);
                    }
                    mx = dpp_max16(mx);
                    float sum = 0.f;
#pragma unroll
                    for (int n = 0; n < 4; ++n)
                        if (vals[n] > -INFINITY) sum += __expf(vals[n] - mx);
                    sum = dpp_sum16(sum);
                    if (r == 0) {
                        int row = row0 + m * 16 + kq * 4 + rr;
                        partials[(size_t)row * NCHUNK + chunk] = make_float2(mx, sum);
                    }
                }
            }
        }
    }
}

// ---------------- flash attention: QBLK=128, 8 waves, reg-staged K/V, DPP softmax ----------------
__global__ __launch_bounds__(512, 4) void flash_attn_kernel(const bf16* __restrict__ qkv,
                                                            bf16* __restrict__ ctx) {
    __shared__ short Ks[128 * 64];       // K tile [kv][64 d], granule ^= kv&7
    __shared__ short Vt[64 * 128];       // V^T tile [d][128 kv], granule ^= d&7
    __shared__ short Ps[8][16][132];     // per-wave P tile [qrow][kv], padded

    int tid = threadIdx.x, lane = tid & 63, w = tid >> 6;   // 8 waves
    int r = lane & 15, kq = lane >> 4;
    int qt = (int)gridDim.x - 1 - (int)blockIdx.x;           // longest first
    int q0 = qt * 128;
    int bh = blockIdx.y;
    int b = bh / NHEADS, h = bh % NHEADS;
    const int RS = 3 * DM;

    const bf16* qbase = qkv + (size_t)(b * TSEQ + q0 + w * 16 + r) * RS + h * 64;
    bf16x8 qf[2];
    qf[0] = *reinterpret_cast<const bf16x8*>(qbase + kq * 8);
    qf[1] = *reinterpret_cast<const bf16x8*>(qbase + 32 + kq * 8);

    f32x4 of[4] = {};
    float mrow[4] = {-INFINITY, -INFINITY, -INFINITY, -INFINITY};
    float lrow[4] = {};

    int stid = tid & 255;
    int kvq = stid >> 3;                 // 0..31 -> kv rows kvq*4..+3
    int d0 = (stid & 7) * 8;
    bool isK = tid < 256;
    const bf16* sb0 = qkv + (size_t)(b * TSEQ) * RS + (isK ? DM : 2 * DM) + h * 64;
    bf16x8 r0, r1, r2, r3;

    auto loadKV = [&](int t) {
        const bf16* p = sb0 + (size_t)(t * 128 + kvq * 4) * RS + d0;
        r0 = *reinterpret_cast<const bf16x8*>(p);
        r1 = *reinterpret_cast<const bf16x8*>(p + RS);
        r2 = *reinterpret_cast<const bf16x8*>(p + 2 * RS);
        r3 = *reinterpret_cast<const bf16x8*>(p + 3 * RS);
    };
    auto writeKV = [&]() {
        if (isK) {
            bf16x8 rs[4] = {r0, r1, r2, r3};
#pragma unroll
            for (int j = 0; j < 4; ++j) {
                int kv = kvq * 4 + j;
                int pg = (stid & 7) ^ (kv & 7);
                *reinterpret_cast<bf16x8*>(&Ks[kv * 64 + pg * 8]) = rs[j];
            }
        } else {
            int lg = kvq >> 1, half = kvq & 1;
#pragma unroll
            for (int jj = 0; jj < 8; ++jj) {
                int d = d0 + jj;
                int phys = lg ^ (d & 7);
                s16x4 pk = {r0[jj], r1[jj], r2[jj], r3[jj]};
                *reinterpret_cast<s16x4*>(&Vt[d * 128 + phys * 8 + half * 4]) = pk;
            }
        }
    };

    int ntiles = qt + 1;
    loadKV(0);
    for (int t = 0; t < ntiles; ++t) {
        __syncthreads();                 // prior tile's LDS reads done
        writeKV();
        __syncthreads();                 // publish Ks/Vt
        if (t + 1 < ntiles) loadKV(t + 1);   // lands under this tile's compute

        int kv0 = t * 128;
        // ---- QK^T: 16 MFMA ----
        f32x4 sf[8];
#pragma unroll
        for (int n = 0; n < 8; ++n) sf[n] = (f32x4){0.f, 0.f, 0.f, 0.f};
        __builtin_amdgcn_s_setprio(1);
#pragma unroll
        for (int n = 0; n < 8; ++n) {
            int row = n * 16 + r;
#pragma unroll
            for (int kt = 0; kt < 2; ++kt) {
                int gran = (kt * 4 + kq) ^ (row & 7);
                bf16x8 kf = *reinterpret_cast<bf16x8*>(&Ks[row * 64 + gran * 8]);
                sf[n] = MFMA16(qf[kt], kf, sf[n]);
            }
        }
        __builtin_amdgcn_s_setprio(0);

        // ---- online softmax over 128 cols (DPP 16-lane reductions) ----
        bool diag = (kv0 + 128 > q0);
        float alpha[4];
#pragma unroll
        for (int rr = 0; rr < 4; ++rr) {
            int qrow = q0 + w * 16 + kq * 4 + rr;
            float vals[8];
            float mx = mrow[rr];
#pragma unroll
            for (int n = 0; n < 8; ++n) {
                float v = sf[n][rr] * 0.125f;
                if (diag && (kv0 + n * 16 + r) > qrow) v = -INFINITY;
                vals[n] = v;
                mx = fmaxf(mx, v);
            }
            mx = dpp_max16(mx);
            float al = __expf(mrow[rr] - mx);
            float sum = 0.f;
#pragma unroll
            for (int n = 0; n < 8; ++n) {
                float p = __expf(vals[n] - mx);
                vals[n] = p;
                sum += p;
            }
            sum = dpp_sum16(sum);
            mrow[rr] = mx;
            lrow[rr] = lrow[rr] * al + sum;
            alpha[rr] = al;
#pragma unroll
            for (int n = 0; n < 8; ++n) Ps[w][kq * 4 + rr][n * 16 + r] = f2bf(vals[n]);
        }
#pragma unroll
        for (int n = 0; n < 4; ++n)
#pragma unroll
            for (int rr = 0; rr < 4; ++rr) of[n][rr] *= alpha[rr];

        // ---- PV: 16 MFMA ----
        __builtin_amdgcn_s_setprio(1);
#pragma unroll
        for (int kt = 0; kt < 4; ++kt) {
            bf16x8 pa = *reinterpret_cast<bf16x8*>(&Ps[w][r][kt * 32 + kq * 8]);
#pragma unroll
            for (int n = 0; n < 4; ++n) {
                int row = n * 16 + r;
                int gran = (kt * 4 + kq) ^ (row & 7);
                bf16x8 vf = *reinterpret_cast<bf16x8*>(&Vt[row * 128 + gran * 8]);
                of[n] = MFMA16(pa, vf, of[n]);
            }
        }
        __builtin_amdgcn_s_setprio(0);
    }

    // ---- epilogue ----
#pragma unroll
    for (int rr = 0; rr < 4; ++rr) {
        float inv = 1.0f / lrow[rr];
        int qrow = q0 + w * 16 + kq * 4 + rr;
        bf16* cb = ctx + (size_t)(b * TSEQ + qrow) * DM + h * 64;
#pragma unroll
        for (int n = 0; n < 4; ++n) cb[n * 16 + r] = (bf16)(of[n][rr] * inv);
    }
}

// ---------------- loss: merge per-chunk partials ----------------
__global__ __launch_bounds__(256) void loss_reduce_kernel(const float2* __restrict__ partials,
                                                          const float* __restrict__ logits,
                                                          const int* __restrict__ target,
                                                          float* __restrict__ nll) {
    int row = blockIdx.x, tid = threadIdx.x;
    const float2* pr = partials + (size_t)row * NCHUNK;
    float m = -INFINITY, s = 0.f;
    for (int c = tid; c < NCHUNK; c += 256) {
        float2 p = pr[c];
        if (p.x > m) { s = s * __expf(m - p.x) + p.y; m = p.x; }
        else         { s += p.y * __expf(p.x - m); }
    }
    __shared__ float sm[256], ssum[256];
    sm[tid] = m; ssum[tid] = s; __syncthreads();
    for (int o = 128; o; o >>= 1) {
        if (tid < o) {
            float m2 = sm[tid + o], s2 = ssum[tid + o];
            float mm = fmaxf(sm[tid], m2);
            ssum[tid] = ssum[tid] * __expf(sm[tid] - mm) + s2 * __expf(m2 - mm);
            sm[tid] = mm;
        }
        __syncthreads();
    }
    if (tid == 0) {
        float lse = sm[0] + logf(ssum[0]);
        nll[row] = lse - logits[(size_t)row * VOCAB + target[row]];
    }
}

__global__ void loss2_kernel(const float* __restrict__ nll, float* __restrict__ loss) {
    int tid = threadIdx.x;
    float s = 0.f;
    for (int i = tid; i < BT; i += 1024) s += nll[i];
    __shared__ float r[1024];
    r[tid] = s; __syncthreads();
    for (int o = 512; o; o >>= 1) { if (tid < o) r[tid] += r[tid + o]; __syncthreads(); }
    if (tid == 0) *loss = r[0] * (1.0f / BT);
}

// ---------------- launcher ----------------
extern "C" void kernel_launch(void* const* d_in, const int* in_sizes, int n_in,
                              void* d_out, int out_size, void* d_ws, size_t ws_size,
                              hipStream_t stream) {
    const int*   inp    = (const int*)  d_in[0];
    const int*   target = (const int*)  d_in[1];
    const float* wte    = (const float*)d_in[2];
    const float* wpe    = (const float*)d_in[3];
    const float* ln1_w  = (const float*)d_in[4];
    const float* ln1_b  = (const float*)d_in[5];
    const float* attn_w = (const float*)d_in[6];
    const float* attn_b = (const float*)d_in[7];
    const float* proj_w = (const float*)d_in[8];
    const float* proj_b = (const float*)d_in[9];
    const float* ln2_w  = (const float*)d_in[10];
    const float* ln2_b  = (const float*)d_in[11];
    const float* fc_w   = (const float*)d_in[12];
    const float* fc_b   = (const float*)d_in[13];
    const float* fc2_w  = (const float*)d_in[14];
    const float* fc2_b  = (const float*)d_in[15];
    const float* lnf_w  = (const float*)d_in[16];
    const float* lnf_b  = (const float*)d_in[17];
    float* out = (float*)d_out;

    char* p = (char*)d_ws;
    auto alloc = [&](size_t bytes) { char* q = p; p += (bytes + 255) & ~(size_t)255; return q; };
    float* x     = (float*)alloc((size_t)BT * DM * 4);
    float* nll   = (float*)alloc((size_t)BT * 4);
    bf16*  qkvb  = (bf16*) alloc((size_t)BT * 3 * DM * 2);
    bf16*  tmpb  = (bf16*) alloc((size_t)BT * DM * 2);
    bf16*  ctxb  = (bf16*) alloc((size_t)BT * DM * 2);
    bf16*  hb    = (bf16*) alloc((size_t)BT * 4 * DM * 2);
    bf16*  wteb  = (bf16*) alloc((size_t)VOCAB * DM * 2);
    bf16*  wqkvT = (bf16*) alloc((size_t)NLAYERS * 3 * DM * DM * 2);
    bf16*  wprojT= (bf16*) alloc((size_t)NLAYERS * DM * DM * 2);
    bf16*  wfcT  = (bf16*) alloc((size_t)NLAYERS * 4 * DM * DM * 2);
    bf16*  wfc2T = (bf16*) alloc((size_t)NLAYERS * 4 * DM * DM * 2);
    // loss partials (25.8 MB) alias the ctxb+hb region (31.5 MB, dead after layer loop)
    float2* partials = (float2*)ctxb;

    dim3 tb(32, 8);
    transpose_bf16_kernel<<<dim3(3 * DM / 32, DM / 32, NLAYERS), tb, 0, stream>>>(attn_w, wqkvT, DM, 3 * DM);
    transpose_bf16_kernel<<<dim3(DM / 32, DM / 32, NLAYERS), tb, 0, stream>>>(proj_w, wprojT, DM, DM);
    transpose_bf16_kernel<<<dim3(4 * DM / 32, DM / 32, NLAYERS), tb, 0, stream>>>(fc_w, wfcT, DM, 4 * DM);
    transpose_bf16_kernel<<<dim3(DM / 32, 4 * DM / 32, NLAYERS), tb, 0, stream>>>(fc2_w, wfc2T, 4 * DM, DM);
    {
        size_t n4 = (size_t)VOCAB * DM / 4;
        tobf16_kernel<<<(unsigned)((n4 + 255) / 256), 256, 0, stream>>>(wte, wteb, n4);
    }

    embed_kernel<<<BT * DM / 4 / 256, 256, 0, stream>>>(inp, wte, wpe, x);

    for (int i = 0; i < NLAYERS; ++i) {
        ln_kernel<<<BT / 4, 256, 0, stream>>>(x, ln1_w + i * DM, ln1_b + i * DM, tmpb);
        gemm_k<GF_OBF16, 0><<<dim3(BT / 128, 3 * DM / 128), 256, 0, stream>>>(
            tmpb, wqkvT + (size_t)i * 3 * DM * DM, attn_b + i * 3 * DM, nullptr,
            qkvb, nullptr, BT, 3 * DM, DM);
        flash_attn_kernel<<<dim3(TSEQ / 128, 4 * NHEADS), 512, 0, stream>>>(qkvb, ctxb);
        gemm_k64<0, 1><<<dim3(BT / 64, DM / 128), 256, 0, stream>>>(
            ctxb, wprojT + (size_t)i * DM * DM, proj_b + i * DM, x,
            x, nullptr, BT, DM, DM);
        ln_kernel<<<BT / 4, 256, 0, stream>>>(x, ln2_w + i * DM, ln2_b + i * DM, tmpb);
        gemm_k<GF_GELU | GF_OBF16, 2><<<dim3(BT / 128, 4 * DM / 128), 256, 0, stream>>>(
            tmpb, wfcT + (size_t)i * 4 * DM * DM, fc_b + i * 4 * DM, nullptr,
            hb, nullptr, BT, 4 * DM, DM);
        gemm_k64<0, 3><<<dim3(BT / 64, DM / 128), 256, 0, stream>>>(
            hb, wfc2T + (size_t)i * 4 * DM * DM, fc2_b + i * DM, x,
            x, nullptr, BT, DM, 4 * DM);
    }

    ln_kernel<<<BT / 4, 256, 0, stream>>>(x, lnf_w, lnf_b, tmpb);
    gemm_wide<GF_CLAMP | GF_PARTIAL, 4><<<dim3(BT / 128, (VOCAB + 255) / 256), 512, 0, stream>>>(
        tmpb, wteb, nullptr, nullptr, out, partials, BT, VOCAB, DM);
    loss_reduce_kernel<<<BT, 256, 0, stream>>>(partials, out, target, nll);
    loss2_kernel<<<1, 1024, 0, stream>>>(nll, out + (size_t)out_size - 1);
}

// Round 16
// 3619.095 us; speedup vs baseline: 1.2029x; 1.2029x over previous
//
#include <hip/hip_runtime.h>
#include <hip/hip_bf16.h>
#include <cmath>

#define NLAYERS 12
#define NHEADS  12
#define DM      768
#define VOCAB   50257
#define TSEQ    1024
#define BT      4096   // B*T
#define NCHUNK  786    // ceil(VOCAB/64) col-chunks for loss partials

typedef __attribute__((ext_vector_type(4))) float f32x4;
typedef __attribute__((ext_vector_type(8))) short bf16x8;
typedef __attribute__((ext_vector_type(4))) short s16x4;

typedef __hip_bfloat16 bf16;

#define MFMA16(a, b, c) __builtin_amdgcn_mfma_f32_16x16x32_bf16(a, b, c, 0, 0, 0)

// ---------------- helpers ----------------
__device__ __forceinline__ void gload16(const void* g, void* l) {
    __builtin_amdgcn_global_load_lds(
        (const __attribute__((address_space(1))) void*)g,
        (__attribute__((address_space(3))) void*)l, 16, 0, 0);
}

// raw s_barrier with compiler memory fences (no forced vmcnt(0) drain)
__device__ __forceinline__ void wg_barrier() {
    asm volatile("" ::: "memory");
    __builtin_amdgcn_s_barrier();
    asm volatile("" ::: "memory");
}

__device__ __forceinline__ float gelu_tanh(float v) {
    float u = 0.7978845608028654f * (v + 0.044715f * v * v * v);
    return 0.5f * v * (1.0f + tanhf(u));
}

__device__ __forceinline__ short f2bf(float f) {
    bf16 h = (bf16)f;
    return *reinterpret_cast<short*>(&h);
}

// ---- DPP 16-lane butterfly reductions (VALU-speed, no LDS/bpermute) ----
template<int CTRL>
__device__ __forceinline__ float dpp_mov(float x) {
    int i = __builtin_bit_cast(int, x);
    i = __builtin_amdgcn_mov_dpp(i, CTRL, 0xF, 0xF, false);
    return __builtin_bit_cast(float, i);
}
__device__ __forceinline__ float dpp_max16(float x) {
    x = fmaxf(x, dpp_mov<0xB1>(x));
    x = fmaxf(x, dpp_mov<0x4E>(x));
    x = fmaxf(x, dpp_mov<0x141>(x));
    x = fmaxf(x, dpp_mov<0x140>(x));
    return x;
}
__device__ __forceinline__ float dpp_sum16(float x) {
    x += dpp_mov<0xB1>(x);
    x += dpp_mov<0x4E>(x);
    x += dpp_mov<0x141>(x);
    x += dpp_mov<0x140>(x);
    return x;
}

struct ushort4s { short a, b, c, d; };

// ---------------- weight prep ----------------
__global__ void transpose_bf16_kernel(const float* __restrict__ in, bf16* __restrict__ out,
                                      int K, int N) {
    __shared__ float tile[32][33];
    size_t lofs = (size_t)blockIdx.z * K * N;
    int k0 = blockIdx.y * 32, n0 = blockIdx.x * 32;
    int tx = threadIdx.x, ty = threadIdx.y;      // 32x8
#pragma unroll
    for (int i = 0; i < 32; i += 8)
        tile[ty + i][tx] = in[lofs + (size_t)(k0 + ty + i) * N + n0 + tx];
    __syncthreads();
#pragma unroll
    for (int i = 0; i < 32; i += 8)
        out[lofs + (size_t)(n0 + ty + i) * K + k0 + tx] = (bf16)tile[tx][ty + i];
}

__global__ void tobf16_kernel(const float* __restrict__ in, bf16* __restrict__ out, size_t n4) {
    size_t i = (size_t)blockIdx.x * 256 + threadIdx.x;
    if (i < n4) {
        float4 f = reinterpret_cast<const float4*>(in)[i];
        s16x4 o = {f2bf(f.x), f2bf(f.y), f2bf(f.z), f2bf(f.w)};
        *reinterpret_cast<s16x4*>(out + i * 4) = o;
    }
}

// ---------------- embedding (fp32 residual stream, float4) ----------------
__global__ void embed_kernel(const int* __restrict__ inp, const float* __restrict__ wte,
                             const float* __restrict__ wpe, float* __restrict__ x) {
    int idx = blockIdx.x * 256 + threadIdx.x;    // over BT*DM/4
    int m = idx / (DM / 4), c4 = idx % (DM / 4);
    int tok = inp[m];
    int t = m & (TSEQ - 1);
    float4 a = reinterpret_cast<const float4*>(wte)[(size_t)tok * (DM / 4) + c4];
    float4 b = reinterpret_cast<const float4*>(wpe)[(size_t)t * (DM / 4) + c4];
    float4 o = {a.x + b.x, a.y + b.y, a.z + b.z, a.w + b.w};
    reinterpret_cast<float4*>(x)[idx] = o;
}

// ---------------- layernorm: one row per WAVE (no block sync) ----------------
__global__ __launch_bounds__(256) void ln_kernel(const float* __restrict__ x,
                                                 const float* __restrict__ w,
                                                 const float* __restrict__ b,
                                                 bf16* __restrict__ y) {
    int tid = threadIdx.x, wv = tid >> 6, lane = tid & 63;
    int row = blockIdx.x * 4 + wv;
    const float4* xr = reinterpret_cast<const float4*>(x + (size_t)row * DM);
    float4 v[3];
    float s = 0.f, q = 0.f;
#pragma unroll
    for (int j = 0; j < 3; ++j) {
        v[j] = xr[lane + 64 * j];
        s += v[j].x + v[j].y + v[j].z + v[j].w;
        q += v[j].x * v[j].x + v[j].y * v[j].y + v[j].z * v[j].z + v[j].w * v[j].w;
    }
#pragma unroll
    for (int o = 1; o < 64; o <<= 1) { s += __shfl_xor(s, o); q += __shfl_xor(q, o); }
    float mu  = s * (1.0f / DM);
    float var = q * (1.0f / DM) - mu * mu;
    float inv = rsqrtf(var + 1e-5f);
#pragma unroll
    for (int j = 0; j < 3; ++j) {
        int c4 = lane + 64 * j;
        float4 wv4 = reinterpret_cast<const float4*>(w)[c4];
        float4 bv4 = reinterpret_cast<const float4*>(b)[c4];
        ushort4s o;
        o.a = f2bf((v[j].x - mu) * inv * wv4.x + bv4.x);
        o.b = f2bf((v[j].y - mu) * inv * wv4.y + bv4.y);
        o.c = f2bf((v[j].z - mu) * inv * wv4.z + bv4.z);
        o.d = f2bf((v[j].w - mu) * inv * wv4.w + bv4.w);
        *reinterpret_cast<ushort4s*>(y + (size_t)row * DM + c4 * 4) = o;
    }
}

#define GF_GELU    1
#define GF_OBF16   2
#define GF_CLAMP   4
#define GF_PARTIAL 8

// ---------------- 128x128 GEMM, BK=32, 3-buffer 2-ahead prefetch, counted vmcnt ----------------
template<int FLAGS, int TAG>
__global__ __launch_bounds__(256) void gemm_k(
    const bf16* __restrict__ A, const bf16* __restrict__ Bt,
    const float* __restrict__ bias, const float* __restrict__ resid,
    void* __restrict__ C, float2* __restrict__ partials,
    int M, int N, int K) {
    __shared__ short ldsA[3][128 * 32];
    __shared__ short ldsB[3][128 * 32];
    int tid = threadIdx.x;
    int lane = tid & 63, w = tid >> 6;
    int wm = w >> 1, wn = w & 1;
    int r = lane & 15, kq = lane >> 4;
    int bm = blockIdx.x * 128, bn = blockIdx.y * 128;

    f32x4 acc[4][4] = {};

    auto stage = [&](int buf, int kt) {
        int k0 = kt * 32;
#pragma unroll
        for (int i = 0; i < 2; ++i) {
            int chunk = i * 256 + tid;           // 16B chunk id = row*4 + dest granule
            int row = chunk >> 2;
            int gs = (chunk & 3) ^ ((row >> 1) & 3);   // swizzled source granule
            const bf16* ga = A + (size_t)(bm + row) * K + k0 + gs * 8;
            gload16(ga, &ldsA[buf][(i * 256 + w * 64) * 8]);
            int brow = bn + row;
            const bf16* gb = Bt + (size_t)brow * K + k0 + gs * 8;
            gload16(gb, &ldsB[buf][(i * 256 + w * 64) * 8]);
        }
    };
    auto compute = [&](int buf) {
        bf16x8 af[4], bfr[4];
#pragma unroll
        for (int m = 0; m < 4; ++m) {
            int row = wm * 64 + m * 16 + r;
            af[m] = *reinterpret_cast<bf16x8*>(&ldsA[buf][row * 32 + (kq ^ ((row >> 1) & 3)) * 8]);
        }
#pragma unroll
        for (int n = 0; n < 4; ++n) {
            int row = wn * 64 + n * 16 + r;
            bfr[n] = *reinterpret_cast<bf16x8*>(&ldsB[buf][row * 32 + (kq ^ ((row >> 1) & 3)) * 8]);
        }
        __builtin_amdgcn_s_setprio(1);
#pragma unroll
        for (int m = 0; m < 4; ++m)
#pragma unroll
            for (int n = 0; n < 4; ++n)
                acc[m][n] = MFMA16(af[m], bfr[n], acc[m][n]);
        __builtin_amdgcn_s_setprio(0);
    };

    const int NT = K / 32;
    stage(0, 0);
    stage(1, 1);
    for (int t = 0; t < NT; ++t) {
        if (t + 2 < NT) {
            stage((t + 2) % 3, t + 2);
            asm volatile("s_waitcnt vmcnt(8)" ::: "memory");   // tile t landed
        } else if (t + 1 < NT) {
            asm volatile("s_waitcnt vmcnt(4)" ::: "memory");
        } else {
            asm volatile("s_waitcnt vmcnt(0)" ::: "memory");
        }
        wg_barrier();                    // tile t resident for ALL waves
        compute(t % 3);
        asm volatile("s_waitcnt lgkmcnt(0)" ::: "memory");     // my reads done
        wg_barrier();                    // publish: buffer reusable
    }

    int row0 = bm + wm * 64, col0 = bn + wn * 64;
#pragma unroll
    for (int m = 0; m < 4; ++m) {
#pragma unroll
        for (int n = 0; n < 4; ++n) {
            int col = col0 + n * 16 + r;
#pragma unroll
            for (int rr = 0; rr < 4; ++rr) {
                int row = row0 + m * 16 + kq * 4 + rr;
                float v = acc[m][n][rr];
                if (bias) v += bias[col];
                if (FLAGS & GF_GELU) v = gelu_tanh(v);
                if (resid) v += resid[(size_t)row * N + col];
                if (FLAGS & GF_OBF16) ((bf16*)C)[(size_t)row * N + col] = (bf16)v;
                else                  ((float*)C)[(size_t)row * N + col] = v;
            }
        }
    }
}

// ---------------- 64x128 GEMM, BK=32, 3-buffer 2-ahead (proj / fc2) ----------------
template<int FLAGS, int TAG>
__global__ __launch_bounds__(256) void gemm_k64(
    const bf16* __restrict__ A, const bf16* __restrict__ Bt,
    const float* __restrict__ bias, const float* __restrict__ resid,
    void* __restrict__ C, float2* __restrict__ partials,
    int M, int N, int K) {
    __shared__ short ldsA[3][64 * 32];
    __shared__ short ldsB[3][128 * 32];
    int tid = threadIdx.x;
    int lane = tid & 63, w = tid >> 6;           // 4 waves, wave w: cols w*32..+31
    int r = lane & 15, kq = lane >> 4;
    int bm = blockIdx.x * 64, bn = blockIdx.y * 128;

    f32x4 acc[4][2] = {};

    auto stage = [&](int buf, int kt) {
        int k0 = kt * 32;
        {   // A tile: 64 rows x 4 granules = 256 chunks, 1/thread
            int row = tid >> 2;
            int gs = (tid & 3) ^ ((row >> 1) & 3);
            gload16(A + (size_t)(bm + row) * K + k0 + gs * 8, &ldsA[buf][tid * 8]);
        }
#pragma unroll
        for (int i = 0; i < 2; ++i) {            // B tile: 128 rows x 4 = 512 chunks, 2/thread
            int chunk = i * 256 + tid;
            int row = chunk >> 2;
            int gs = (chunk & 3) ^ ((row >> 1) & 3);
            gload16(Bt + (size_t)(bn + row) * K + k0 + gs * 8, &ldsB[buf][chunk * 8]);
        }
    };
    auto compute = [&](int buf) {
        bf16x8 af[4], bfr[2];
#pragma unroll
        for (int m = 0; m < 4; ++m) {
            int row = m * 16 + r;
            af[m] = *reinterpret_cast<bf16x8*>(&ldsA[buf][row * 32 + (kq ^ ((row >> 1) & 3)) * 8]);
        }
#pragma unroll
        for (int n = 0; n < 2; ++n) {
            int row = w * 32 + n * 16 + r;
            bfr[n] = *reinterpret_cast<bf16x8*>(&ldsB[buf][row * 32 + (kq ^ ((row >> 1) & 3)) * 8]);
        }
        __builtin_amdgcn_s_setprio(1);
#pragma unroll
        for (int m = 0; m < 4; ++m)
#pragma unroll
            for (int n = 0; n < 2; ++n)
                acc[m][n] = MFMA16(af[m], bfr[n], acc[m][n]);
        __builtin_amdgcn_s_setprio(0);
    };

    const int NT = K / 32;
    stage(0, 0);
    stage(1, 1);
    for (int t = 0; t < NT; ++t) {
        if (t + 2 < NT) {
            stage((t + 2) % 3, t + 2);
            asm volatile("s_waitcnt vmcnt(6)" ::: "memory");   // tile t landed
        } else if (t + 1 < NT) {
            asm volatile("s_waitcnt vmcnt(3)" ::: "memory");
        } else {
            asm volatile("s_waitcnt vmcnt(0)" ::: "memory");
        }
        wg_barrier();
        compute(t % 3);
        asm volatile("s_waitcnt lgkmcnt(0)" ::: "memory");
        wg_barrier();
    }

    int col0 = bn + w * 32;
#pragma unroll
    for (int m = 0; m < 4; ++m) {
#pragma unroll
        for (int n = 0; n < 2; ++n) {
            int col = col0 + n * 16 + r;
#pragma unroll
            for (int rr = 0; rr < 4; ++rr) {
                int row = bm + m * 16 + kq * 4 + rr;
                float v = acc[m][n][rr];
                if (bias) v += bias[col];
                if (FLAGS & GF_GELU) v = gelu_tanh(v);
                if (resid) v += resid[(size_t)row * N + col];
                if (FLAGS & GF_OBF16) ((bf16*)C)[(size_t)row * N + col] = (bf16)v;
                else                  ((float*)C)[(size_t)row * N + col] = v;
            }
        }
    }
}

// ---------------- 128x256 GEMM, 8 waves x 64x64, 3-buffer 2-ahead (lm_head) ----------------
template<int FLAGS, int TAG>
__global__ __launch_bounds__(512, 4) void gemm_wide(
    const bf16* __restrict__ A, const bf16* __restrict__ Bt,
    const float* __restrict__ bias, const float* __restrict__ resid,
    void* __restrict__ C, float2* __restrict__ partials,
    int M, int N, int K) {
    __shared__ short ldsA[3][128 * 32];          // 3 x 8 KB
    __shared__ short ldsB[3][256 * 32];          // 3 x 16 KB
    int tid = threadIdx.x;                       // 0..511
    int lane = tid & 63, w = tid >> 6;
    int wm = w >> 2, wn = w & 3;                 // 2M x 4N waves, 64x64 each
    int r = lane & 15, kq = lane >> 4;
    int bm = blockIdx.x * 128, bn = blockIdx.y * 256;

    f32x4 acc[4][4] = {};

    auto stage = [&](int buf, int kt) {
        int k0 = kt * 32;
        {   // A tile: 512 chunks, 1 per thread
            int row = tid >> 2;
            int gs = (tid & 3) ^ ((row >> 1) & 3);
            gload16(A + (size_t)(bm + row) * K + k0 + gs * 8, &ldsA[buf][tid * 8]);
        }
#pragma unroll
        for (int i = 0; i < 2; ++i) {            // B tile: 1024 chunks, 2 per thread
            int chunk = i * 512 + tid;
            int row = chunk >> 2;
            int gs = (chunk & 3) ^ ((row >> 1) & 3);
            int grow = bn + row;
            if (FLAGS & GF_CLAMP) grow = min(grow, N - 1);
            gload16(Bt + (size_t)grow * K + k0 + gs * 8, &ldsB[buf][chunk * 8]);
        }
    };
    auto compute = [&](int buf) {
        bf16x8 af[4], bfr[4];
#pragma unroll
        for (int m = 0; m < 4; ++m) {
            int row = wm * 64 + m * 16 + r;
            af[m] = *reinterpret_cast<bf16x8*>(&ldsA[buf][row * 32 + (kq ^ ((row >> 1) & 3)) * 8]);
        }
#pragma unroll
        for (int n = 0; n < 4; ++n) {
            int row = wn * 64 + n * 16 + r;
            bfr[n] = *reinterpret_cast<bf16x8*>(&ldsB[buf][row * 32 + (kq ^ ((row >> 1) & 3)) * 8]);
        }
        __builtin_amdgcn_s_setprio(1);
#pragma unroll
        for (int m = 0; m < 4; ++m)
#pragma unroll
            for (int n = 0; n < 4; ++n)
                acc[m][n] = MFMA16(af[m], bfr[n], acc[m][n]);
        __builtin_amdgcn_s_setprio(0);
    };

    const int NT = K / 32;                       // 24
    stage(0, 0);
    stage(1, 1);
    for (int t = 0; t < NT; ++t) {
        if (t + 2 < NT) {
            stage((t + 2) % 3, t + 2);
            asm volatile("s_waitcnt vmcnt(6)" ::: "memory");   // tile t landed
        } else if (t + 1 < NT) {
            asm volatile("s_waitcnt vmcnt(3)" ::: "memory");
        } else {
            asm volatile("s_waitcnt vmcnt(0)" ::: "memory");
        }
        wg_barrier();
        compute(t % 3);
        asm volatile("s_waitcnt lgkmcnt(0)" ::: "memory");
        wg_barrier();
    }

    int row0 = bm + wm * 64, col0 = bn + wn * 64;
#pragma unroll
    for (int m = 0; m < 4; ++m) {
#pragma unroll
        for (int n = 0; n < 4; ++n) {
            int col = col0 + n * 16 + r;
            if (col < N) {
#pragma unroll
                for (int rr = 0; rr < 4; ++rr) {
                    int row = row0 + m * 16 + kq * 4 + rr;
                    float v = acc[m][n][rr];
                    if (bias) v += bias[col];
                    if (FLAGS & GF_GELU) v = gelu_tanh(v);
                    if (resid) v += resid[(size_t)row * N + col];
                    if (FLAGS & GF_OBF16) ((bf16*)C)[(size_t)row * N + col] = (bf16)v;
                    else                  ((float*)C)[(size_t)row * N + col] = v;
                }
            }
        }
    }

    if (FLAGS & GF_PARTIAL) {
        int chunk = (bn >> 6) + wn;              // 64-col chunk index
        if (chunk < NCHUNK) {
#pragma unroll
            for (int m = 0; m < 4; ++m) {
#pragma unroll
                for (int rr = 0; rr < 4; ++rr) {
                    float vals[4], mx = -INFINITY;
#pragma unroll
                    for (int n = 0; n < 4; ++n) {
                        int col = col0 + n * 16 + r;
                        float v = (col < N) ? acc[m][n][rr] : -INFINITY;
                        vals[n] = v;
                        mx = fmaxf(mx, v);
                    }
                    mx = dpp_max16(mx);
                    float sum = 0.f;
#pragma unroll
                    for (int n = 0; n < 4; ++n)
                        if (vals[n] > -INFINITY) sum += __expf(vals[n] - mx);
                    sum = dpp_sum16(sum);
                    if (r == 0) {
                        int row = row0 + m * 16 + kq * 4 + rr;
                        partials[(size_t)row * NCHUNK + chunk] = make_float2(mx, sum);
                    }
                }
            }
        }
    }
}

// ---------------- flash attention: QBLK=128, 8 waves, reg-staged K/V, DPP softmax ----------------
__global__ __launch_bounds__(512, 4) void flash_attn_kernel(const bf16* __restrict__ qkv,
                                                            bf16* __restrict__ ctx) {
    __shared__ short Ks[128 * 64];       // K tile [kv][64 d], granule ^= kv&7
    __shared__ short Vt[64 * 128];       // V^T tile [d][128 kv], granule ^= d&7
    __shared__ short Ps[8][16][132];     // per-wave P tile [qrow][kv], padded

    int tid = threadIdx.x, lane = tid & 63, w = tid >> 6;   // 8 waves
    int r = lane & 15, kq = lane >> 4;
    int qt = (int)gridDim.x - 1 - (int)blockIdx.x;           // longest first
    int q0 = qt * 128;
    int bh = blockIdx.y;
    int b = bh / NHEADS, h = bh % NHEADS;
    const int RS = 3 * DM;

    const bf16* qbase = qkv + (size_t)(b * TSEQ + q0 + w * 16 + r) * RS + h * 64;
    bf16x8 qf[2];
    qf[0] = *reinterpret_cast<const bf16x8*>(qbase + kq * 8);
    qf[1] = *reinterpret_cast<const bf16x8*>(qbase + 32 + kq * 8);

    f32x4 of[4] = {};
    float mrow[4] = {-INFINITY, -INFINITY, -INFINITY, -INFINITY};
    float lrow[4] = {};

    int stid = tid & 255;
    int kvq = stid >> 3;                 // 0..31 -> kv rows kvq*4..+3
    int d0 = (stid & 7) * 8;
    bool isK = tid < 256;
    const bf16* sb0 = qkv + (size_t)(b * TSEQ) * RS + (isK ? DM : 2 * DM) + h * 64;
    bf16x8 r0, r1, r2, r3;

    auto loadKV = [&](int t) {
        const bf16* p = sb0 + (size_t)(t * 128 + kvq * 4) * RS + d0;
        r0 = *reinterpret_cast<const bf16x8*>(p);
        r1 = *reinterpret_cast<const bf16x8*>(p + RS);
        r2 = *reinterpret_cast<const bf16x8*>(p + 2 * RS);
        r3 = *reinterpret_cast<const bf16x8*>(p + 3 * RS);
    };
    auto writeKV = [&]() {
        if (isK) {
            bf16x8 rs[4] = {r0, r1, r2, r3};
#pragma unroll
            for (int j = 0; j < 4; ++j) {
                int kv = kvq * 4 + j;
                int pg = (stid & 7) ^ (kv & 7);
                *reinterpret_cast<bf16x8*>(&Ks[kv * 64 + pg * 8]) = rs[j];
            }
        } else {
            int lg = kvq >> 1, half = kvq & 1;
#pragma unroll
            for (int jj = 0; jj < 8; ++jj) {
                int d = d0 + jj;
                int phys = lg ^ (d & 7);
                s16x4 pk = {r0[jj], r1[jj], r2[jj], r3[jj]};
                *reinterpret_cast<s16x4*>(&Vt[d * 128 + phys * 8 + half * 4]) = pk;
            }
        }
    };

    int ntiles = qt + 1;
    loadKV(0);
    for (int t = 0; t < ntiles; ++t) {
        __syncthreads();                 // prior tile's LDS reads done
        writeKV();
        __syncthreads();                 // publish Ks/Vt
        if (t + 1 < ntiles) loadKV(t + 1);   // lands under this tile's compute

        int kv0 = t * 128;
        // ---- QK^T: 16 MFMA ----
        f32x4 sf[8];
#pragma unroll
        for (int n = 0; n < 8; ++n) sf[n] = (f32x4){0.f, 0.f, 0.f, 0.f};
        __builtin_amdgcn_s_setprio(1);
#pragma unroll
        for (int n = 0; n < 8; ++n) {
            int row = n * 16 + r;
#pragma unroll
            for (int kt = 0; kt < 2; ++kt) {
                int gran = (kt * 4 + kq) ^ (row & 7);
                bf16x8 kf = *reinterpret_cast<bf16x8*>(&Ks[row * 64 + gran * 8]);
                sf[n] = MFMA16(qf[kt], kf, sf[n]);
            }
        }
        __builtin_amdgcn_s_setprio(0);

        // ---- online softmax over 128 cols (DPP 16-lane reductions) ----
        bool diag = (kv0 + 128 > q0);
        float alpha[4];
#pragma unroll
        for (int rr = 0; rr < 4; ++rr) {
            int qrow = q0 + w * 16 + kq * 4 + rr;
            float vals[8];
            float mx = mrow[rr];
#pragma unroll
            for (int n = 0; n < 8; ++n) {
                float v = sf[n][rr] * 0.125f;
                if (diag && (kv0 + n * 16 + r) > qrow) v = -INFINITY;
                vals[n] = v;
                mx = fmaxf(mx, v);
            }
            mx = dpp_max16(mx);
            float al = __expf(mrow[rr] - mx);
            float sum = 0.f;
#pragma unroll
            for (int n = 0; n < 8; ++n) {
                float p = __expf(vals[n] - mx);
                vals[n] = p;
                sum += p;
            }
            sum = dpp_sum16(sum);
            mrow[rr] = mx;
            lrow[rr] = lrow[rr] * al + sum;
            alpha[rr] = al;
#pragma unroll
            for (int n = 0; n < 8; ++n) Ps[w][kq * 4 + rr][n * 16 + r] = f2bf(vals[n]);
        }
#pragma unroll
        for (int n = 0; n < 4; ++n)
#pragma unroll
            for (int rr = 0; rr < 4; ++rr) of[n][rr] *= alpha[rr];

        // ---- PV: 16 MFMA ----
        __builtin_amdgcn_s_setprio(1);
#pragma unroll
        for (int kt = 0; kt < 4; ++kt) {
            bf16x8 pa = *reinterpret_cast<bf16x8*>(&Ps[w][r][kt * 32 + kq * 8]);
#pragma unroll
            for (int n = 0; n < 4; ++n) {
                int row = n * 16 + r;
                int gran = (kt * 4 + kq) ^ (row & 7);
                bf16x8 vf = *reinterpret_cast<bf16x8*>(&Vt[row * 128 + gran * 8]);
                of[n] = MFMA16(pa, vf, of[n]);
            }
        }
        __builtin_amdgcn_s_setprio(0);
    }

    // ---- epilogue ----
#pragma unroll
    for (int rr = 0; rr < 4; ++rr) {
        float inv = 1.0f / lrow[rr];
        int qrow = q0 + w * 16 + kq * 4 + rr;
        bf16* cb = ctx + (size_t)(b * TSEQ + qrow) * DM + h * 64;
#pragma unroll
        for (int n = 0; n < 4; ++n) cb[n * 16 + r] = (bf16)(of[n][rr] * inv);
    }
}

// ---------------- loss: merge per-chunk partials ----------------
__global__ __launch_bounds__(256) void loss_reduce_kernel(const float2* __restrict__ partials,
                                                          const float* __restrict__ logits,
                                                          const int* __restrict__ target,
                                                          float* __restrict__ nll) {
    int row = blockIdx.x, tid = threadIdx.x;
    const float2* pr = partials + (size_t)row * NCHUNK;
    float m = -INFINITY, s = 0.f;
    for (int c = tid; c < NCHUNK; c += 256) {
        float2 p = pr[c];
        if (p.x > m) { s = s * __expf(m - p.x) + p.y; m = p.x; }
        else         { s += p.y * __expf(p.x - m); }
    }
    __shared__ float sm[256], ssum[256];
    sm[tid] = m; ssum[tid] = s; __syncthreads();
    for (int o = 128; o; o >>= 1) {
        if (tid < o) {
            float m2 = sm[tid + o], s2 = ssum[tid + o];
            float mm = fmaxf(sm[tid], m2);
            ssum[tid] = ssum[tid] * __expf(sm[tid] - mm) + s2 * __expf(m2 - mm);
            sm[tid] = mm;
        }
        __syncthreads();
    }
    if (tid == 0) {
        float lse = sm[0] + logf(ssum[0]);
        nll[row] = lse - logits[(size_t)row * VOCAB + target[row]];
    }
}

__global__ void loss2_kernel(const float* __restrict__ nll, float* __restrict__ loss) {
    int tid = threadIdx.x;
    float s = 0.f;
    for (int i = tid; i < BT; i += 1024) s += nll[i];
    __shared__ float r[1024];
    r[tid] = s; __syncthreads();
    for (int o = 512; o; o >>= 1) { if (tid < o) r[tid] += r[tid + o]; __syncthreads(); }
    if (tid == 0) *loss = r[0] * (1.0f / BT);
}

// ---------------- launcher ----------------
extern "C" void kernel_launch(void* const* d_in, const int* in_sizes, int n_in,
                              void* d_out, int out_size, void* d_ws, size_t ws_size,
                              hipStream_t stream) {
    const int*   inp    = (const int*)  d_in[0];
    const int*   target = (const int*)  d_in[1];
    const float* wte    = (const float*)d_in[2];
    const float* wpe    = (const float*)d_in[3];
    const float* ln1_w  = (const float*)d_in[4];
    const float* ln1_b  = (const float*)d_in[5];
    const float* attn_w = (const float*)d_in[6];
    const float* attn_b = (const float*)d_in[7];
    const float* proj_w = (const float*)d_in[8];
    const float* proj_b = (const float*)d_in[9];
    const float* ln2_w  = (const float*)d_in[10];
    const float* ln2_b  = (const float*)d_in[11];
    const float* fc_w   = (const float*)d_in[12];
    const float* fc_b   = (const float*)d_in[13];
    const float* fc2_w  = (const float*)d_in[14];
    const float* fc2_b  = (const float*)d_in[15];
    const float* lnf_w  = (const float*)d_in[16];
    const float* lnf_b  = (const float*)d_in[17];
    float* out = (float*)d_out;

    char* p = (char*)d_ws;
    auto alloc = [&](size_t bytes) { char* q = p; p += (bytes + 255) & ~(size_t)255; return q; };
    float* x     = (float*)alloc((size_t)BT * DM * 4);
    float* nll   = (float*)alloc((size_t)BT * 4);
    bf16*  qkvb  = (bf16*) alloc((size_t)BT * 3 * DM * 2);
    bf16*  tmpb  = (bf16*) alloc((size_t)BT * DM * 2);
    bf16*  ctxb  = (bf16*) alloc((size_t)BT * DM * 2);
    bf16*  hb    = (bf16*) alloc((size_t)BT * 4 * DM * 2);
    bf16*  wteb  = (bf16*) alloc((size_t)VOCAB * DM * 2);
    bf16*  wqkvT = (bf16*) alloc((size_t)NLAYERS * 3 * DM * DM * 2);
    bf16*  wprojT= (bf16*) alloc((size_t)NLAYERS * DM * DM * 2);
    bf16*  wfcT  = (bf16*) alloc((size_t)NLAYERS * 4 * DM * DM * 2);
    bf16*  wfc2T = (bf16*) alloc((size_t)NLAYERS * 4 * DM * DM * 2);
    // loss partials (25.8 MB) alias the ctxb+hb region (31.5 MB, dead after layer loop)
    float2* partials = (float2*)ctxb;

    dim3 tb(32, 8);
    transpose_bf16_kernel<<<dim3(3 * DM / 32, DM / 32, NLAYERS), tb, 0, stream>>>(attn_w, wqkvT, DM, 3 * DM);
    transpose_bf16_kernel<<<dim3(DM / 32, DM / 32, NLAYERS), tb, 0, stream>>>(proj_w, wprojT, DM, DM);
    transpose_bf16_kernel<<<dim3(4 * DM / 32, DM / 32, NLAYERS), tb, 0, stream>>>(fc_w, wfcT, DM, 4 * DM);
    transpose_bf16_kernel<<<dim3(DM / 32, 4 * DM / 32, NLAYERS), tb, 0, stream>>>(fc2_w, wfc2T, 4 * DM, DM);
    {
        size_t n4 = (size_t)VOCAB * DM / 4;
        tobf16_kernel<<<(unsigned)((n4 + 255) / 256), 256, 0, stream>>>(wte, wteb, n4);
    }

    embed_kernel<<<BT * DM / 4 / 256, 256, 0, stream>>>(inp, wte, wpe, x);

    for (int i = 0; i < NLAYERS; ++i) {
        ln_kernel<<<BT / 4, 256, 0, stream>>>(x, ln1_w + i * DM, ln1_b + i * DM, tmpb);
        gemm_k<GF_OBF16, 0><<<dim3(BT / 128, 3 * DM / 128), 256, 0, stream>>>(
            tmpb, wqkvT + (size_t)i * 3 * DM * DM, attn_b + i * 3 * DM, nullptr,
            qkvb, nullptr, BT, 3 * DM, DM);
        flash_attn_kernel<<<dim3(TSEQ / 128, 4 * NHEADS), 512, 0, stream>>>(qkvb, ctxb);
        gemm_k64<0, 1><<<dim3(BT / 64, DM / 128), 256, 0, stream>>>(
            ctxb, wprojT + (size_t)i * DM * DM, proj_b + i * DM, x,
            x, nullptr, BT, DM, DM);
        ln_kernel<<<BT / 4, 256, 0, stream>>>(x, ln2_w + i * DM, ln2_b + i * DM, tmpb);
        gemm_k<GF_GELU | GF_OBF16, 2><<<dim3(BT / 128, 4 * DM / 128), 256, 0, stream>>>(
            tmpb, wfcT + (size_t)i * 4 * DM * DM, fc_b + i * 4 * DM, nullptr,
            hb, nullptr, BT, 4 * DM, DM);
        gemm_k64<0, 3><<<dim3(BT / 64, DM / 128), 256, 0, stream>>>(
            hb, wfc2T + (size_t)i * 4 * DM * DM, fc2_b + i * DM, x,
            x, nullptr, BT, DM, 4 * DM);
    }

    ln_kernel<<<BT / 4, 256, 0, stream>>>(x, lnf_w, lnf_b, tmpb);
    gemm_wide<GF_CLAMP | GF_PARTIAL, 4><<<dim3(BT / 128, (VOCAB + 255) / 256), 512, 0, stream>>>(
        tmpb, wteb, nullptr, nullptr, out, partials, BT, VOCAB, DM);
    loss_reduce_kernel<<<BT, 256, 0, stream>>>(partials, out, target, nll);
    loss2_kernel<<<1, 1024, 0, stream>>>(nll, out + (size_t)out_size - 1);
}

// Round 17
// 3547.734 us; speedup vs baseline: 1.2271x; 1.0201x over previous
//
#include <hip/hip_runtime.h>
#include <hip/hip_bf16.h>
#include <cmath>

#define NLAYERS 12
#define NHEADS  12
#define DM      768
#define VOCAB   50257
#define TSEQ    1024
#define BT      4096   // B*T
#define NCHUNK  786    // ceil(VOCAB/64) col-chunks for loss partials

typedef __attribute__((ext_vector_type(4))) float f32x4;
typedef __attribute__((ext_vector_type(8))) short bf16x8;
typedef __attribute__((ext_vector_type(4))) short s16x4;

typedef __hip_bfloat16 bf16;

#define MFMA16(a, b, c) __builtin_amdgcn_mfma_f32_16x16x32_bf16(a, b, c, 0, 0, 0)

// ---------------- helpers ----------------
__device__ __forceinline__ void gload16(const void* g, void* l) {
    __builtin_amdgcn_global_load_lds(
        (const __attribute__((address_space(1))) void*)g,
        (__attribute__((address_space(3))) void*)l, 16, 0, 0);
}

// raw s_barrier with compiler memory fences (no forced vmcnt(0) drain)
__device__ __forceinline__ void wg_barrier() {
    asm volatile("" ::: "memory");
    __builtin_amdgcn_s_barrier();
    asm volatile("" ::: "memory");
}

__device__ __forceinline__ float gelu_tanh(float v) {
    float u = 0.7978845608028654f * (v + 0.044715f * v * v * v);
    return 0.5f * v * (1.0f + tanhf(u));
}

__device__ __forceinline__ short f2bf(float f) {
    bf16 h = (bf16)f;
    return *reinterpret_cast<short*>(&h);
}

// ---- DPP 16-lane butterfly reductions (VALU-speed, no LDS/bpermute) ----
template<int CTRL>
__device__ __forceinline__ float dpp_mov(float x) {
    int i = __builtin_bit_cast(int, x);
    i = __builtin_amdgcn_mov_dpp(i, CTRL, 0xF, 0xF, false);
    return __builtin_bit_cast(float, i);
}
__device__ __forceinline__ float dpp_max16(float x) {
    x = fmaxf(x, dpp_mov<0xB1>(x));
    x = fmaxf(x, dpp_mov<0x4E>(x));
    x = fmaxf(x, dpp_mov<0x141>(x));
    x = fmaxf(x, dpp_mov<0x140>(x));
    return x;
}
__device__ __forceinline__ float dpp_sum16(float x) {
    x += dpp_mov<0xB1>(x);
    x += dpp_mov<0x4E>(x);
    x += dpp_mov<0x141>(x);
    x += dpp_mov<0x140>(x);
    return x;
}

struct ushort4s { short a, b, c, d; };

// ---------------- weight prep ----------------
__global__ void transpose_bf16_kernel(const float* __restrict__ in, bf16* __restrict__ out,
                                      int K, int N) {
    __shared__ float tile[32][33];
    size_t lofs = (size_t)blockIdx.z * K * N;
    int k0 = blockIdx.y * 32, n0 = blockIdx.x * 32;
    int tx = threadIdx.x, ty = threadIdx.y;      // 32x8
#pragma unroll
    for (int i = 0; i < 32; i += 8)
        tile[ty + i][tx] = in[lofs + (size_t)(k0 + ty + i) * N + n0 + tx];
    __syncthreads();
#pragma unroll
    for (int i = 0; i < 32; i += 8)
        out[lofs + (size_t)(n0 + ty + i) * K + k0 + tx] = (bf16)tile[tx][ty + i];
}

__global__ void tobf16_kernel(const float* __restrict__ in, bf16* __restrict__ out, size_t n4) {
    size_t i = (size_t)blockIdx.x * 256 + threadIdx.x;
    if (i < n4) {
        float4 f = reinterpret_cast<const float4*>(in)[i];
        s16x4 o = {f2bf(f.x), f2bf(f.y), f2bf(f.z), f2bf(f.w)};
        *reinterpret_cast<s16x4*>(out + i * 4) = o;
    }
}

// ---------------- embedding (fp32 residual stream, float4) ----------------
__global__ void embed_kernel(const int* __restrict__ inp, const float* __restrict__ wte,
                             const float* __restrict__ wpe, float* __restrict__ x) {
    int idx = blockIdx.x * 256 + threadIdx.x;    // over BT*DM/4
    int m = idx / (DM / 4), c4 = idx % (DM / 4);
    int tok = inp[m];
    int t = m & (TSEQ - 1);
    float4 a = reinterpret_cast<const float4*>(wte)[(size_t)tok * (DM / 4) + c4];
    float4 b = reinterpret_cast<const float4*>(wpe)[(size_t)t * (DM / 4) + c4];
    float4 o = {a.x + b.x, a.y + b.y, a.z + b.z, a.w + b.w};
    reinterpret_cast<float4*>(x)[idx] = o;
}

// ---------------- layernorm: one row per WAVE (no block sync) ----------------
__global__ __launch_bounds__(256) void ln_kernel(const float* __restrict__ x,
                                                 const float* __restrict__ w,
                                                 const float* __restrict__ b,
                                                 bf16* __restrict__ y) {
    int tid = threadIdx.x, wv = tid >> 6, lane = tid & 63;
    int row = blockIdx.x * 4 + wv;
    const float4* xr = reinterpret_cast<const float4*>(x + (size_t)row * DM);
    float4 v[3];
    float s = 0.f, q = 0.f;
#pragma unroll
    for (int j = 0; j < 3; ++j) {
        v[j] = xr[lane + 64 * j];
        s += v[j].x + v[j].y + v[j].z + v[j].w;
        q += v[j].x * v[j].x + v[j].y * v[j].y + v[j].z * v[j].z + v[j].w * v[j].w;
    }
#pragma unroll
    for (int o = 1; o < 64; o <<= 1) { s += __shfl_xor(s, o); q += __shfl_xor(q, o); }
    float mu  = s * (1.0f / DM);
    float var = q * (1.0f / DM) - mu * mu;
    float inv = rsqrtf(var + 1e-5f);
#pragma unroll
    for (int j = 0; j < 3; ++j) {
        int c4 = lane + 64 * j;
        float4 wv4 = reinterpret_cast<const float4*>(w)[c4];
        float4 bv4 = reinterpret_cast<const float4*>(b)[c4];
        ushort4s o;
        o.a = f2bf((v[j].x - mu) * inv * wv4.x + bv4.x);
        o.b = f2bf((v[j].y - mu) * inv * wv4.y + bv4.y);
        o.c = f2bf((v[j].z - mu) * inv * wv4.z + bv4.z);
        o.d = f2bf((v[j].w - mu) * inv * wv4.w + bv4.w);
        *reinterpret_cast<ushort4s*>(y + (size_t)row * DM + c4 * 4) = o;
    }
}

#define GF_GELU    1
#define GF_OBF16   2
#define GF_CLAMP   4
#define GF_PARTIAL 8

// ---------------- 128x128 GEMM, BK=32, 3-buffer 2-ahead prefetch, counted vmcnt ----------------
template<int FLAGS, int TAG>
__global__ __launch_bounds__(256) void gemm_k(
    const bf16* __restrict__ A, const bf16* __restrict__ Bt,
    const float* __restrict__ bias, const float* __restrict__ resid,
    void* __restrict__ C, float2* __restrict__ partials,
    int M, int N, int K) {
    __shared__ short ldsA[3][128 * 32];
    __shared__ short ldsB[3][128 * 32];
    int tid = threadIdx.x;
    int lane = tid & 63, w = tid >> 6;
    int wm = w >> 1, wn = w & 1;
    int r = lane & 15, kq = lane >> 4;
    int bm = blockIdx.x * 128, bn = blockIdx.y * 128;

    f32x4 acc[4][4] = {};

    auto stage = [&](int buf, int kt) {
        int k0 = kt * 32;
#pragma unroll
        for (int i = 0; i < 2; ++i) {
            int chunk = i * 256 + tid;           // 16B chunk id = row*4 + dest granule
            int row = chunk >> 2;
            int gs = (chunk & 3) ^ ((row >> 1) & 3);   // swizzled source granule
            const bf16* ga = A + (size_t)(bm + row) * K + k0 + gs * 8;
            gload16(ga, &ldsA[buf][(i * 256 + w * 64) * 8]);
            int brow = bn + row;
            const bf16* gb = Bt + (size_t)brow * K + k0 + gs * 8;
            gload16(gb, &ldsB[buf][(i * 256 + w * 64) * 8]);
        }
    };
    auto compute = [&](int buf) {
        bf16x8 af[4], bfr[4];
#pragma unroll
        for (int m = 0; m < 4; ++m) {
            int row = wm * 64 + m * 16 + r;
            af[m] = *reinterpret_cast<bf16x8*>(&ldsA[buf][row * 32 + (kq ^ ((row >> 1) & 3)) * 8]);
        }
#pragma unroll
        for (int n = 0; n < 4; ++n) {
            int row = wn * 64 + n * 16 + r;
            bfr[n] = *reinterpret_cast<bf16x8*>(&ldsB[buf][row * 32 + (kq ^ ((row >> 1) & 3)) * 8]);
        }
        __builtin_amdgcn_s_setprio(1);
#pragma unroll
        for (int m = 0; m < 4; ++m)
#pragma unroll
            for (int n = 0; n < 4; ++n)
                acc[m][n] = MFMA16(af[m], bfr[n], acc[m][n]);
        __builtin_amdgcn_s_setprio(0);
    };

    const int NT = K / 32;
    stage(0, 0);
    stage(1, 1);
    for (int t = 0; t < NT; ++t) {
        if (t + 2 < NT) {
            stage((t + 2) % 3, t + 2);
            asm volatile("s_waitcnt vmcnt(8)" ::: "memory");   // tile t landed
        } else if (t + 1 < NT) {
            asm volatile("s_waitcnt vmcnt(4)" ::: "memory");
        } else {
            asm volatile("s_waitcnt vmcnt(0)" ::: "memory");
        }
        wg_barrier();                    // tile t resident for ALL waves
        compute(t % 3);
        asm volatile("s_waitcnt lgkmcnt(0)" ::: "memory");     // my reads done
        wg_barrier();                    // publish: buffer reusable
    }

    int row0 = bm + wm * 64, col0 = bn + wn * 64;
#pragma unroll
    for (int m = 0; m < 4; ++m) {
#pragma unroll
        for (int n = 0; n < 4; ++n) {
            int col = col0 + n * 16 + r;
#pragma unroll
            for (int rr = 0; rr < 4; ++rr) {
                int row = row0 + m * 16 + kq * 4 + rr;
                float v = acc[m][n][rr];
                if (bias) v += bias[col];
                if (FLAGS & GF_GELU) v = gelu_tanh(v);
                if (resid) v += resid[(size_t)row * N + col];
                if (FLAGS & GF_OBF16) ((bf16*)C)[(size_t)row * N + col] = (bf16)v;
                else                  ((float*)C)[(size_t)row * N + col] = v;
            }
        }
    }
}

// ---------------- 64x128 GEMM, BK=32, 4-buffer 2-ahead, SINGLE barrier/K-step ----------------
// Order per iter: stage(t+2) -> counted vmcnt -> barrier -> compute(t).
// Race-freedom with 4 buffers: stage target (t+2)%4 vs slowest wave still in
// compute(t-1) reading (t-1)%4 -- distinct mod 4; all other pairs separated by
// a barrier whose preceding MFMAs already consumed their ds_reads.
// LDS 4 x 12 KB = 48 KB -> still 3 blocks/CU.
template<int FLAGS, int TAG>
__global__ __launch_bounds__(256) void gemm_k64(
    const bf16* __restrict__ A, const bf16* __restrict__ Bt,
    const float* __restrict__ bias, const float* __restrict__ resid,
    void* __restrict__ C, float2* __restrict__ partials,
    int M, int N, int K) {
    __shared__ short ldsA[4][64 * 32];
    __shared__ short ldsB[4][128 * 32];
    int tid = threadIdx.x;
    int lane = tid & 63, w = tid >> 6;           // 4 waves, wave w: cols w*32..+31
    int r = lane & 15, kq = lane >> 4;
    int bm = blockIdx.x * 64, bn = blockIdx.y * 128;

    f32x4 acc[4][2] = {};

    auto stage = [&](int buf, int kt) {
        int k0 = kt * 32;
        {   // A tile: 64 rows x 4 granules = 256 chunks, 1/thread
            int row = tid >> 2;
            int gs = (tid & 3) ^ ((row >> 1) & 3);
            gload16(A + (size_t)(bm + row) * K + k0 + gs * 8, &ldsA[buf][tid * 8]);
        }
#pragma unroll
        for (int i = 0; i < 2; ++i) {            // B tile: 128 rows x 4 = 512 chunks, 2/thread
            int chunk = i * 256 + tid;
            int row = chunk >> 2;
            int gs = (chunk & 3) ^ ((row >> 1) & 3);
            gload16(Bt + (size_t)(bn + row) * K + k0 + gs * 8, &ldsB[buf][chunk * 8]);
        }
    };
    auto compute = [&](int buf) {
        bf16x8 af[4], bfr[2];
#pragma unroll
        for (int m = 0; m < 4; ++m) {
            int row = m * 16 + r;
            af[m] = *reinterpret_cast<bf16x8*>(&ldsA[buf][row * 32 + (kq ^ ((row >> 1) & 3)) * 8]);
        }
#pragma unroll
        for (int n = 0; n < 2; ++n) {
            int row = w * 32 + n * 16 + r;
            bfr[n] = *reinterpret_cast<bf16x8*>(&ldsB[buf][row * 32 + (kq ^ ((row >> 1) & 3)) * 8]);
        }
        __builtin_amdgcn_s_setprio(1);
#pragma unroll
        for (int m = 0; m < 4; ++m)
#pragma unroll
            for (int n = 0; n < 2; ++n)
                acc[m][n] = MFMA16(af[m], bfr[n], acc[m][n]);
        __builtin_amdgcn_s_setprio(0);
    };

    const int NT = K / 32;
    stage(0, 0);
    stage(1, 1);
    for (int t = 0; t < NT; ++t) {
        if (t + 2 < NT) {
            stage((t + 2) & 3, t + 2);
            asm volatile("s_waitcnt vmcnt(6)" ::: "memory");   // tile t landed (2 tiles in flight)
        } else if (t + 1 < NT) {
            asm volatile("s_waitcnt vmcnt(3)" ::: "memory");
        } else {
            asm volatile("s_waitcnt vmcnt(0)" ::: "memory");
        }
        wg_barrier();                    // tile t resident for ALL waves
        compute(t & 3);                  // no trailing barrier: 4-buffer rotation safe
    }

    int col0 = bn + w * 32;
#pragma unroll
    for (int m = 0; m < 4; ++m) {
#pragma unroll
        for (int n = 0; n < 2; ++n) {
            int col = col0 + n * 16 + r;
#pragma unroll
            for (int rr = 0; rr < 4; ++rr) {
                int row = bm + m * 16 + kq * 4 + rr;
                float v = acc[m][n][rr];
                if (bias) v += bias[col];
                if (FLAGS & GF_GELU) v = gelu_tanh(v);
                if (resid) v += resid[(size_t)row * N + col];
                if (FLAGS & GF_OBF16) ((bf16*)C)[(size_t)row * N + col] = (bf16)v;
                else                  ((float*)C)[(size_t)row * N + col] = v;
            }
        }
    }
}

// ---------------- 128x256 GEMM, 8 waves x 64x64, 3-buffer 2-ahead (lm_head) ----------------
template<int FLAGS, int TAG>
__global__ __launch_bounds__(512, 4) void gemm_wide(
    const bf16* __restrict__ A, const bf16* __restrict__ Bt,
    const float* __restrict__ bias, const float* __restrict__ resid,
    void* __restrict__ C, float2* __restrict__ partials,
    int M, int N, int K) {
    __shared__ short ldsA[3][128 * 32];          // 3 x 8 KB
    __shared__ short ldsB[3][256 * 32];          // 3 x 16 KB
    int tid = threadIdx.x;                       // 0..511
    int lane = tid & 63, w = tid >> 6;
    int wm = w >> 2, wn = w & 3;                 // 2M x 4N waves, 64x64 each
    int r = lane & 15, kq = lane >> 4;
    int bm = blockIdx.x * 128, bn = blockIdx.y * 256;

    f32x4 acc[4][4] = {};

    auto stage = [&](int buf, int kt) {
        int k0 = kt * 32;
        {   // A tile: 512 chunks, 1 per thread
            int row = tid >> 2;
            int gs = (tid & 3) ^ ((row >> 1) & 3);
            gload16(A + (size_t)(bm + row) * K + k0 + gs * 8, &ldsA[buf][tid * 8]);
        }
#pragma unroll
        for (int i = 0; i < 2; ++i) {            // B tile: 1024 chunks, 2 per thread
            int chunk = i * 512 + tid;
            int row = chunk >> 2;
            int gs = (chunk & 3) ^ ((row >> 1) & 3);
            int grow = bn + row;
            if (FLAGS & GF_CLAMP) grow = min(grow, N - 1);
            gload16(Bt + (size_t)grow * K + k0 + gs * 8, &ldsB[buf][chunk * 8]);
        }
    };
    auto compute = [&](int buf) {
        bf16x8 af[4], bfr[4];
#pragma unroll
        for (int m = 0; m < 4; ++m) {
            int row = wm * 64 + m * 16 + r;
            af[m] = *reinterpret_cast<bf16x8*>(&ldsA[buf][row * 32 + (kq ^ ((row >> 1) & 3)) * 8]);
        }
#pragma unroll
        for (int n = 0; n < 4; ++n) {
            int row = wn * 64 + n * 16 + r;
            bfr[n] = *reinterpret_cast<bf16x8*>(&ldsB[buf][row * 32 + (kq ^ ((row >> 1) & 3)) * 8]);
        }
        __builtin_amdgcn_s_setprio(1);
#pragma unroll
        for (int m = 0; m < 4; ++m)
#pragma unroll
            for (int n = 0; n < 4; ++n)
                acc[m][n] = MFMA16(af[m], bfr[n], acc[m][n]);
        __builtin_amdgcn_s_setprio(0);
    };

    const int NT = K / 32;                       // 24
    stage(0, 0);
    stage(1, 1);
    for (int t = 0; t < NT; ++t) {
        if (t + 2 < NT) {
            stage((t + 2) % 3, t + 2);
            asm volatile("s_waitcnt vmcnt(6)" ::: "memory");   // tile t landed
        } else if (t + 1 < NT) {
            asm volatile("s_waitcnt vmcnt(3)" ::: "memory");
        } else {
            asm volatile("s_waitcnt vmcnt(0)" ::: "memory");
        }
        wg_barrier();
        compute(t % 3);
        asm volatile("s_waitcnt lgkmcnt(0)" ::: "memory");
        wg_barrier();
    }

    int row0 = bm + wm * 64, col0 = bn + wn * 64;
#pragma unroll
    for (int m = 0; m < 4; ++m) {
#pragma unroll
        for (int n = 0; n < 4; ++n) {
            int col = col0 + n * 16 + r;
            if (col < N) {
#pragma unroll
                for (int rr = 0; rr < 4; ++rr) {
                    int row = row0 + m * 16 + kq * 4 + rr;
                    float v = acc[m][n][rr];
                    if (bias) v += bias[col];
                    if (FLAGS & GF_GELU) v = gelu_tanh(v);
                    if (resid) v += resid[(size_t)row * N + col];
                    if (FLAGS & GF_OBF16) ((bf16*)C)[(size_t)row * N + col] = (bf16)v;
                    else                  ((float*)C)[(size_t)row * N + col] = v;
                }
            }
        }
    }

    if (FLAGS & GF_PARTIAL) {
        int chunk = (bn >> 6) + wn;              // 64-col chunk index
        if (chunk < NCHUNK) {
#pragma unroll
            for (int m = 0; m < 4; ++m) {
#pragma unroll
                for (int rr = 0; rr < 4; ++rr) {
                    float vals[4], mx = -INFINITY;
#pragma unroll
                    for (int n = 0; n < 4; ++n) {
                        int col = col0 + n * 16 + r;
                        float v = (col < N) ? acc[m][n][rr] : -INFINITY;
                        vals[n] = v;
                        mx = fmaxf(mx, v);
                    }
                    mx = dpp_max16(mx);
                    float sum = 0.f;
#pragma unroll
                    for (int n = 0; n < 4; ++n)
                        if (vals[n] > -INFINITY) sum += __expf(vals[n] - mx);
                    sum = dpp_sum16(sum);
                    if (r == 0) {
                        int row = row0 + m * 16 + kq * 4 + rr;
                        partials[(size_t)row * NCHUNK + chunk] = make_float2(mx, sum);
                    }
                }
            }
        }
    }
}

// ---------------- flash attention: QBLK=128, 8 waves, reg-staged K/V, DPP softmax ----------------
__global__ __launch_bounds__(512, 4) void flash_attn_kernel(const bf16* __restrict__ qkv,
                                                            bf16* __restrict__ ctx) {
    __shared__ short Ks[128 * 64];       // K tile [kv][64 d], granule ^= kv&7
    __shared__ short Vt[64 * 128];       // V^T tile [d][128 kv], granule ^= d&7
    __shared__ short Ps[8][16][132];     // per-wave P tile [qrow][kv], padded

    int tid = threadIdx.x, lane = tid & 63, w = tid >> 6;   // 8 waves
    int r = lane & 15, kq = lane >> 4;
    int qt = (int)gridDim.x - 1 - (int)blockIdx.x;           // longest first
    int q0 = qt * 128;
    int bh = blockIdx.y;
    int b = bh / NHEADS, h = bh % NHEADS;
    const int RS = 3 * DM;

    const bf16* qbase = qkv + (size_t)(b * TSEQ + q0 + w * 16 + r) * RS + h * 64;
    bf16x8 qf[2];
    qf[0] = *reinterpret_cast<const bf16x8*>(qbase + kq * 8);
    qf[1] = *reinterpret_cast<const bf16x8*>(qbase + 32 + kq * 8);

    f32x4 of[4] = {};
    float mrow[4] = {-INFINITY, -INFINITY, -INFINITY, -INFINITY};
    float lrow[4] = {};

    int stid = tid & 255;
    int kvq = stid >> 3;                 // 0..31 -> kv rows kvq*4..+3
    int d0 = (stid & 7) * 8;
    bool isK = tid < 256;
    const bf16* sb0 = qkv + (size_t)(b * TSEQ) * RS + (isK ? DM : 2 * DM) + h * 64;
    bf16x8 r0, r1, r2, r3;

    auto loadKV = [&](int t) {
        const bf16* p = sb0 + (size_t)(t * 128 + kvq * 4) * RS + d0;
        r0 = *reinterpret_cast<const bf16x8*>(p);
        r1 = *reinterpret_cast<const bf16x8*>(p + RS);
        r2 = *reinterpret_cast<const bf16x8*>(p + 2 * RS);
        r3 = *reinterpret_cast<const bf16x8*>(p + 3 * RS);
    };
    auto writeKV = [&]() {
        if (isK) {
            bf16x8 rs[4] = {r0, r1, r2, r3};
#pragma unroll
            for (int j = 0; j < 4; ++j) {
                int kv = kvq * 4 + j;
                int pg = (stid & 7) ^ (kv & 7);
                *reinterpret_cast<bf16x8*>(&Ks[kv * 64 + pg * 8]) = rs[j];
            }
        } else {
            int lg = kvq >> 1, half = kvq & 1;
#pragma unroll
            for (int jj = 0; jj < 8; ++jj) {
                int d = d0 + jj;
                int phys = lg ^ (d & 7);
                s16x4 pk = {r0[jj], r1[jj], r2[jj], r3[jj]};
                *reinterpret_cast<s16x4*>(&Vt[d * 128 + phys * 8 + half * 4]) = pk;
            }
        }
    };

    int ntiles = qt + 1;
    loadKV(0);
    for (int t = 0; t < ntiles; ++t) {
        __syncthreads();                 // prior tile's LDS reads done
        writeKV();
        __syncthreads();                 // publish Ks/Vt
        if (t + 1 < ntiles) loadKV(t + 1);   // lands under this tile's compute

        int kv0 = t * 128;
        // ---- QK^T: 16 MFMA ----
        f32x4 sf[8];
#pragma unroll
        for (int n = 0; n < 8; ++n) sf[n] = (f32x4){0.f, 0.f, 0.f, 0.f};
        __builtin_amdgcn_s_setprio(1);
#pragma unroll
        for (int n = 0; n < 8; ++n) {
            int row = n * 16 + r;
#pragma unroll
            for (int kt = 0; kt < 2; ++kt) {
                int gran = (kt * 4 + kq) ^ (row & 7);
                bf16x8 kf = *reinterpret_cast<bf16x8*>(&Ks[row * 64 + gran * 8]);
                sf[n] = MFMA16(qf[kt], kf, sf[n]);
            }
        }
        __builtin_amdgcn_s_setprio(0);

        // ---- online softmax over 128 cols (DPP 16-lane reductions) ----
        bool diag = (kv0 + 128 > q0);
        float alpha[4];
#pragma unroll
        for (int rr = 0; rr < 4; ++rr) {
            int qrow = q0 + w * 16 + kq * 4 + rr;
            float vals[8];
            float mx = mrow[rr];
#pragma unroll
            for (int n = 0; n < 8; ++n) {
                float v = sf[n][rr] * 0.125f;
                if (diag && (kv0 + n * 16 + r) > qrow) v = -INFINITY;
                vals[n] = v;
                mx = fmaxf(mx, v);
            }
            mx = dpp_max16(mx);
            float al = __expf(mrow[rr] - mx);
            float sum = 0.f;
#pragma unroll
            for (int n = 0; n < 8; ++n) {
                float p = __expf(vals[n] - mx);
                vals[n] = p;
                sum += p;
            }
            sum = dpp_sum16(sum);
            mrow[rr] = mx;
            lrow[rr] = lrow[rr] * al + sum;
            alpha[rr] = al;
#pragma unroll
            for (int n = 0; n < 8; ++n) Ps[w][kq * 4 + rr][n * 16 + r] = f2bf(vals[n]);
        }
#pragma unroll
        for (int n = 0; n < 4; ++n)
#pragma unroll
            for (int rr = 0; rr < 4; ++rr) of[n][rr] *= alpha[rr];

        // ---- PV: 16 MFMA ----
        __builtin_amdgcn_s_setprio(1);
#pragma unroll
        for (int kt = 0; kt < 4; ++kt) {
            bf16x8 pa = *reinterpret_cast<bf16x8*>(&Ps[w][r][kt * 32 + kq * 8]);
#pragma unroll
            for (int n = 0; n < 4; ++n) {
                int row = n * 16 + r;
                int gran = (kt * 4 + kq) ^ (row & 7);
                bf16x8 vf = *reinterpret_cast<bf16x8*>(&Vt[row * 128 + gran * 8]);
                of[n] = MFMA16(pa, vf, of[n]);
            }
        }
        __builtin_amdgcn_s_setprio(0);
    }

    // ---- epilogue ----
#pragma unroll
    for (int rr = 0; rr < 4; ++rr) {
        float inv = 1.0f / lrow[rr];
        int qrow = q0 + w * 16 + kq * 4 + rr;
        bf16* cb = ctx + (size_t)(b * TSEQ + qrow) * DM + h * 64;
#pragma unroll
        for (int n = 0; n < 4; ++n) cb[n * 16 + r] = (bf16)(of[n][rr] * inv);
    }
}

// ---------------- loss: merge per-chunk partials ----------------
__global__ __launch_bounds__(256) void loss_reduce_kernel(const float2* __restrict__ partials,
                                                          const float* __restrict__ logits,
                                                          const int* __restrict__ target,
                                                          float* __restrict__ nll) {
    int row = blockIdx.x, tid = threadIdx.x;
    const float2* pr = partials + (size_t)row * NCHUNK;
    float m = -INFINITY, s = 0.f;
    for (int c = tid; c < NCHUNK; c += 256) {
        float2 p = pr[c];
        if (p.x > m) { s = s * __expf(m - p.x) + p.y; m = p.x; }
        else         { s += p.y * __expf(p.x - m); }
    }
    __shared__ float sm[256], ssum[256];
    sm[tid] = m; ssum[tid] = s; __syncthreads();
    for (int o = 128; o; o >>= 1) {
        if (tid < o) {
            float m2 = sm[tid + o], s2 = ssum[tid + o];
            float mm = fmaxf(sm[tid], m2);
            ssum[tid] = ssum[tid] * __expf(sm[tid] - mm) + s2 * __expf(m2 - mm);
            sm[tid] = mm;
        }
        __syncthreads();
    }
    if (tid == 0) {
        float lse = sm[0] + logf(ssum[0]);
        nll[row] = lse - logits[(size_t)row * VOCAB + target[row]];
    }
}

__global__ void loss2_kernel(const float* __restrict__ nll, float* __restrict__ loss) {
    int tid = threadIdx.x;
    float s = 0.f;
    for (int i = tid; i < BT; i += 1024) s += nll[i];
    __shared__ float r[1024];
    r[tid] = s; __syncthreads();
    for (int o = 512; o; o >>= 1) { if (tid < o) r[tid] += r[tid + o]; __syncthreads(); }
    if (tid == 0) *loss = r[0] * (1.0f / BT);
}

// ---------------- launcher ----------------
extern "C" void kernel_launch(void* const* d_in, const int* in_sizes, int n_in,
                              void* d_out, int out_size, void* d_ws, size_t ws_size,
                              hipStream_t stream) {
    const int*   inp    = (const int*)  d_in[0];
    const int*   target = (const int*)  d_in[1];
    const float* wte    = (const float*)d_in[2];
    const float* wpe    = (const float*)d_in[3];
    const float* ln1_w  = (const float*)d_in[4];
    const float* ln1_b  = (const float*)d_in[5];
    const float* attn_w = (const float*)d_in[6];
    const float* attn_b = (const float*)d_in[7];
    const float* proj_w = (const float*)d_in[8];
    const float* proj_b = (const float*)d_in[9];
    const float* ln2_w  = (const float*)d_in[10];
    const float* ln2_b  = (const float*)d_in[11];
    const float* fc_w   = (const float*)d_in[12];
    const float* fc_b   = (const float*)d_in[13];
    const float* fc2_w  = (const float*)d_in[14];
    const float* fc2_b  = (const float*)d_in[15];
    const float* lnf_w  = (const float*)d_in[16];
    const float* lnf_b  = (const float*)d_in[17];
    float* out = (float*)d_out;

    char* p = (char*)d_ws;
    auto alloc = [&](size_t bytes) { char* q = p; p += (bytes + 255) & ~(size_t)255; return q; };
    float* x     = (float*)alloc((size_t)BT * DM * 4);
    float* nll   = (float*)alloc((size_t)BT * 4);
    bf16*  qkvb  = (bf16*) alloc((size_t)BT * 3 * DM * 2);
    bf16*  tmpb  = (bf16*) alloc((size_t)BT * DM * 2);
    bf16*  ctxb  = (bf16*) alloc((size_t)BT * DM * 2);
    bf16*  hb    = (bf16*) alloc((size_t)BT * 4 * DM * 2);
    bf16*  wteb  = (bf16*) alloc((size_t)VOCAB * DM * 2);
    bf16*  wqkvT = (bf16*) alloc((size_t)NLAYERS * 3 * DM * DM * 2);
    bf16*  wprojT= (bf16*) alloc((size_t)NLAYERS * DM * DM * 2);
    bf16*  wfcT  = (bf16*) alloc((size_t)NLAYERS * 4 * DM * DM * 2);
    bf16*  wfc2T = (bf16*) alloc((size_t)NLAYERS * 4 * DM * DM * 2);
    // loss partials (25.8 MB) alias the ctxb+hb region (31.5 MB, dead after layer loop)
    float2* partials = (float2*)ctxb;

    dim3 tb(32, 8);
    transpose_bf16_kernel<<<dim3(3 * DM / 32, DM / 32, NLAYERS), tb, 0, stream>>>(attn_w, wqkvT, DM, 3 * DM);
    transpose_bf16_kernel<<<dim3(DM / 32, DM / 32, NLAYERS), tb, 0, stream>>>(proj_w, wprojT, DM, DM);
    transpose_bf16_kernel<<<dim3(4 * DM / 32, DM / 32, NLAYERS), tb, 0, stream>>>(fc_w, wfcT, DM, 4 * DM);
    transpose_bf16_kernel<<<dim3(DM / 32, 4 * DM / 32, NLAYERS), tb, 0, stream>>>(fc2_w, wfc2T, 4 * DM, DM);
    {
        size_t n4 = (size_t)VOCAB * DM / 4;
        tobf16_kernel<<<(unsigned)((n4 + 255) / 256), 256, 0, stream>>>(wte, wteb, n4);
    }

    embed_kernel<<<BT * DM / 4 / 256, 256, 0, stream>>>(inp, wte, wpe, x);

    for (int i = 0; i < NLAYERS; ++i) {
        ln_kernel<<<BT / 4, 256, 0, stream>>>(x, ln1_w + i * DM, ln1_b + i * DM, tmpb);
        gemm_k<GF_OBF16, 0><<<dim3(BT / 128, 3 * DM / 128), 256, 0, stream>>>(
            tmpb, wqkvT + (size_t)i * 3 * DM * DM, attn_b + i * 3 * DM, nullptr,
            qkvb, nullptr, BT, 3 * DM, DM);
        flash_attn_kernel<<<dim3(TSEQ / 128, 4 * NHEADS), 512, 0, stream>>>(qkvb, ctxb);
        gemm_k64<0, 1><<<dim3(BT / 64, DM / 128), 256, 0, stream>>>(
            ctxb, wprojT + (size_t)i * DM * DM, proj_b + i * DM, x,
            x, nullptr, BT, DM, DM);
        ln_kernel<<<BT / 4, 256, 0, stream>>>(x, ln2_w + i * DM, ln2_b + i * DM, tmpb);
        gemm_k<GF_GELU | GF_OBF16, 2><<<dim3(BT / 128, 4 * DM / 128), 256, 0, stream>>>(
            tmpb, wfcT + (size_t)i * 4 * DM * DM, fc_b + i * 4 * DM, nullptr,
            hb, nullptr, BT, 4 * DM, DM);
        gemm_k64<0, 3><<<dim3(BT / 64, DM / 128), 256, 0, stream>>>(
            hb, wfc2T + (size_t)i * 4 * DM * DM, fc2_b + i * DM, x,
            x, nullptr, BT, DM, 4 * DM);
    }

    ln_kernel<<<BT / 4, 256, 0, stream>>>(x, lnf_w, lnf_b, tmpb);
    gemm_wide<GF_CLAMP | GF_PARTIAL, 4><<<dim3(BT / 128, (VOCAB + 255) / 256), 512, 0, stream>>>(
        tmpb, wteb, nullptr, nullptr, out, partials, BT, VOCAB, DM);
    loss_reduce_kernel<<<BT, 256, 0, stream>>>(partials, out, target, nll);
    loss2_kernel<<<1, 1024, 0, stream>>>(nll, out + (size_t)out_size - 1);
}